// Round 2
// 232.710 us; speedup vs baseline: 1.0600x; 1.0600x over previous
//
#include <hip/hip_runtime.h>
#include <math.h>

// ---------------------------------------------------------------------------
// S4 conv:  y[b,l,h] = sum_{t<=l} K[2047-(l-t)]*u[t,h] + D*u[l,h]
//   A[l][t] = krev[2047-l+t], krev[x] = K[x]; D folded into krev[2047].
// prep_quant (block 0): expm(dt*A) via order-9 Taylor + scaling/squaring;
//   B_bar fp64 solve; log-depth doubling scans -> K; emits pre-shifted
//   ring tables rg_hi/rg_lo (16B groups krev16[e..e+7]) + cutoff.
// prep_quant (blocks 1..2048): quantize u -> bf16 B-fragment layout (ubf).
// conv (512 blocks): 128x128 bf16 MFMA, 2-product (Khi,Klo); tiles paired
//   (bm, 15-bm) for perfect balance; b-frags direct-global, prefetched.
//
// R4->R5: block-0 serial chain was the bottleneck (rocprof: occupancy 3%,
// VALUBusy 2.3% over a 105us dispatch => single-block tail). mm64 rewritten:
//   - f32x4 accumulators, broadcast-scalar*vector FMAs -> v_pk_fma_f32
//     (halves VALU issue: 512 pk vs 1024 scalar per thread)
//   - swizzle masks hoisted: (k4+d)&28==k4&28, (r0+i)&28==r0&28 for the
//     aligned tile bases -> address math is 2 XORs per k-step
//   - unroll 8 k-steps for LDS-latency hiding at 1 wave/SIMD
// Taylor threshold 0.5 -> 1.0 (err ~7e-7 << bf16 u-quant err): sExp=E not E+1.
// ||A||_1 via factorized P_j * suffix-sum(P) with shfl scan (was O(64) serial
// fp64-sqrt loop per lane).
// (R5 resubmit: previous bench attempt died on container acquisition, not on
// the kernel.)
// ---------------------------------------------------------------------------

typedef short short8 __attribute__((ext_vector_type(8)));
typedef float f32x4 __attribute__((ext_vector_type(4)));

#define SWMASK 28
__device__ __forceinline__ int swz(int r, int c) {
  return (r << 6) + (c ^ (r & SWMASK));
}
__device__ __forceinline__ float Aval(int i, int j) {
  if (i > j)  return -(float)(sqrt(2.0 * i + 1.0) * sqrt(2.0 * j + 1.0));
  if (i == j) return -(float)(i + 1);
  return 0.0f;
}
__device__ __forceinline__ unsigned rne_bf16(float x) {
  unsigned u = __float_as_uint(x);
  return (u + 0x7FFFu + ((u >> 16) & 1u)) >> 16;
}
__device__ __forceinline__ float invfact(int k) {
  switch (k) {
    case 0: return 1.0f;            case 1: return 1.0f;
    case 2: return 0.5f;            case 3: return (float)(1.0/6.0);
    case 4: return (float)(1.0/24.0);       case 5: return (float)(1.0/120.0);
    case 6: return (float)(1.0/720.0);      case 7: return (float)(1.0/5040.0);
    case 8: return (float)(1.0/40320.0);    default: return (float)(1.0/362880.0);
  }
}

// 64x64x64 fp32 matmul in swizzled LDS. out = L*R (+ cI*I + cX*Xg if addG).
// Each thread: 4 rows x 4 cols. Row base r0 and col base c0 are 4-aligned,
// k4 is 4-aligned, so the XOR swizzle masks are loop-/lane-invariant:
//   a[i] addr col = k4 ^ (r0&28)   (same for all i)
//   b[d] addr col = c0 ^ (k4&28)   (same for all d)
__device__ __forceinline__ void mm64(float* out, const float* L, const float* R,
                                     const float* Xg, float cI, float cX,
                                     int addG, int tid) {
  __syncthreads();
  const int r0 = (tid & 15) << 2;
  const int c0 = (tid >> 4) << 2;
  const int rm = r0 & SWMASK;      // invariant across i (i<4, r0 4-aligned)
  const int cswz = c0 ^ rm;        // output/G column offset, invariant
  f32x4 acc[4];
#pragma unroll
  for (int i = 0; i < 4; ++i) acc[i] = (f32x4){0.f, 0.f, 0.f, 0.f};

#pragma unroll 8
  for (int k4 = 0; k4 < 64; k4 += 4) {
    const int ka = k4 ^ rm;            // a-column offset this step
    const int cm = c0 ^ (k4 & SWMASK); // b-column offset this step
    f32x4 a[4], bv[4];
#pragma unroll
    for (int i = 0; i < 4; ++i)
      a[i] = *(const f32x4*)&L[((r0 + i) << 6) + ka];
#pragma unroll
    for (int d = 0; d < 4; ++d)
      bv[d] = *(const f32x4*)&R[((k4 + d) << 6) + cm];
#pragma unroll
    for (int i = 0; i < 4; ++i) {
#pragma unroll
      for (int d = 0; d < 4; ++d)
        acc[i] = a[i][d] * bv[d] + acc[i];   // -> v_pk_fma_f32 pairs
    }
  }
  if (addG) {
#pragma unroll
    for (int i = 0; i < 4; ++i) {
      f32x4 xv = *(const f32x4*)&Xg[((r0 + i) << 6) + cswz];
      acc[i] = cX * xv + acc[i];
#pragma unroll
      for (int j = 0; j < 4; ++j)
        if (r0 + i == c0 + j) acc[i][j] += cI;
    }
  }
#pragma unroll
  for (int i = 0; i < 4; ++i)
    *(f32x4*)&out[((r0 + i) << 6) + cswz] = acc[i];
  __syncthreads();
}

__global__ __launch_bounds__(256) void prep_quant(
    const float* __restrict__ u, const float* __restrict__ B_ssm,
    const float* __restrict__ C_ssm, const float* __restrict__ D_skip,
    const float* __restrict__ log_dt, uint4* __restrict__ rg_hi,
    uint4* __restrict__ rg_lo, int* __restrict__ wsi,
    uint4* __restrict__ ubf) {
  __shared__ __align__(16) float smem[16384];  // 64 KB
  const int tid = threadIdx.x;

  if (blockIdx.x != 0) {
    // ---------------- u-quant block: (b, tc, half) -> ubf ----------------
    int q = blockIdx.x - 1;                 // 0..2047
    int b = q >> 7, rem = q & 127;
    int tc = rem >> 1, hf = rem & 1;
    int t0 = (tc << 5) + (hf << 4);
    float* S = smem;                        // [16][520]
#pragma unroll
    for (int r = 0; r < 8; ++r) {
      int s = tid + (r << 8);               // 2048 float4-slots
      int row = s >> 7, c4 = (s & 127) << 2;
      float4 v = *(const float4*)(u + ((((b << 11) + t0 + row) << 9) + c4));
      *(float4*)&S[row * 520 + c4] = v;
    }
    __syncthreads();
#pragma unroll
    for (int r = 0; r < 4; ++r) {
      int gidx = tid + (r << 8);            // 0..1023
      int jnG = gidx >> 5;                  // 0..31
      int gl = (gidx >> 4) & 1;
      int hm = gidx & 15;
      int gg = (hf << 1) | gl;
      int h = (jnG << 4) + hm;
      int tb = gl << 3;
      unsigned pk[4];
#pragma unroll
      for (int q2 = 0; q2 < 4; ++q2) {
        unsigned lo = rne_bf16(S[(tb + 2 * q2) * 520 + h]);
        unsigned hi = rne_bf16(S[(tb + 2 * q2 + 1) * 520 + h]);
        pk[q2] = lo | (hi << 16);
      }
      ubf[(((b << 6) | tc) << 11) | (jnG << 6) | (gg << 4) | hm] =
          make_uint4(pk[0], pk[1], pk[2], pk[3]);
    }
    return;
  }

  // ---------------- prep block ----------------
  float* b0 = smem;
  float* b1 = smem + 4096;
  float* b2 = smem + 8192;
  float* b3 = smem + 12288;
  const int lane = tid & 63, wv = tid >> 6;
  const float dtf = expf(log_dt[0]);

  // ||A||_1 column sums: cs[j] = (j+1) + P_j * sum_{i>j} P_i
  // (factorized; suffix sum of P via log-depth shuffle scan)
  if (tid < 64) {
    double p = sqrt(2.0 * tid + 1.0);
    double s = p;
#pragma unroll
    for (int off = 1; off < 64; off <<= 1) {
      double t = __shfl_down(s, off, 64);
      if (tid + off < 64) s += t;
    }
    b2[tid] = (float)((tid + 1.0) + p * (s - p));
  }
  __syncthreads();
  float maxc = 0.f;
  for (int j = 0; j < 64; ++j) maxc = fmaxf(maxc, b2[j]);
  int E;
  frexpf(dtf * maxc, &E);
  int sExp = E > 0 ? E : 0;  // eta/2^s <= 1.0; order-9 err ~7e-7 (ok in fp32)
  const float scale = ldexpf(dtf, -sExp);
  __syncthreads();

  // X -> b0
  for (int idx = tid; idx < 4096; idx += 256) {
    int r = idx >> 6, c = idx & 63;
    b0[swz(r, c)] = scale * Aval(r, c);
  }
  // X2 -> b1
  mm64(b1, b0, b0, b0, 0.f, 0.f, 0, tid);
  // G = c8*I + c9*X -> b2; Horner m=3..0: P = P*X2 + (c2m*I + c2m+1*X)
  for (int idx = tid; idx < 4096; idx += 256) {
    int r = idx >> 6, c = idx & 63;
    float gv = invfact(9) * b0[swz(r, c)];
    if (r == c) gv += invfact(8);
    b2[swz(r, c)] = gv;
  }
  float* Pc = b2;
  float* Pn = b3;
#pragma unroll
  for (int mq = 3; mq >= 0; --mq) {
    mm64(Pn, Pc, b1, b0, invfact(2 * mq), invfact(2 * mq + 1), 1, tid);
    float* t = Pc; Pc = Pn; Pn = t;
  }
  for (int q = 0; q < sExp; ++q) {
    mm64(Pn, Pc, Pc, b0, 0.f, 0.f, 0, tid);
    float* t = Pc; Pc = Pn; Pn = t;
  }
  // Pc = A_bar = M_0.  X, X2 dead -> Vt/Wt regions.
  float* Vt = b0;          // [64][68] spills into b1[0..255]
  float* Wt = b1 + 256;    // [32][68]
  float* Bl = b1 + 2500;   // 64 floats
  if (tid < 64) Bl[tid] = B_ssm[tid];
  __syncthreads();

  // B_bar: solve A x = (A_bar - I) B  (fp64, wave 0)
  // NOTE: swizzled float4 read of row i gives columns k4*4..k4*4+3 in
  // ascending order (XOR cancels) -> plain operand indexed at k4*4.
  if (tid < 64) {
    int i = tid;
    double accd = 0.0;
#pragma unroll
    for (int k4 = 0; k4 < 16; ++k4) {
      int jM = (k4 << 2) ^ (i & 28);
      float4 mv = *(const float4*)&Pc[(i << 6) + jM];
      float4 bv = *(const float4*)&Bl[k4 << 2];
      accd += (double)mv.x * bv.x + (double)mv.y * bv.y +
              (double)mv.z * bv.z + (double)mv.w * bv.w;
    }
    accd -= (double)Bl[i];
    double xv = 0.0;
    for (int j = 0; j < 64; ++j) {
      if (i == j) xv = accd / (double)Aval(j, j);
      double xj = __shfl(xv, j, 64);
      if (i > j) accd -= (double)Aval(i, j) * xj;
    }
    Vt[i] = (float)xv;  // Vt[0][i] = B_bar
  }
  __syncthreads();

  // V doubling: v_{t+2^k} = M_k v_t  (Pc = M_k), then square
  for (int k = 0; k < 6; ++k) {
    int cnt = 1 << k;
    for (int t = wv; t < cnt; t += 4) {
      float accv = 0.f;
#pragma unroll
      for (int k4 = 0; k4 < 16; ++k4) {
        int jM = (k4 << 2) ^ (lane & 28);
        float4 mv = *(const float4*)&Pc[(lane << 6) + jM];
        float4 vvv = *(const float4*)&Vt[t * 68 + (k4 << 2)];
        accv += mv.x * vvv.x + mv.y * vvv.y + mv.z * vvv.z + mv.w * vvv.w;
      }
      Vt[(t + cnt) * 68 + lane] = accv;
    }
    mm64(Pn, Pc, Pc, b0, 0.f, 0.f, 0, tid);  // leading barrier covers Vt
    float* t2 = Pc; Pc = Pn; Pn = t2;
  }
  // Pc = R = A_bar^64. Transpose -> Pn, continue chain on R^T.
  for (int idx = tid; idx < 4096; idx += 256) {
    int r = idx >> 6, c = idx & 63;
    Pn[swz(c, r)] = Pc[swz(r, c)];
  }
  __syncthreads();
  { float* t2 = Pc; Pc = Pn; Pn = t2; }
  if (tid < 64) Wt[lane] = C_ssm[lane];  // w_0 = C
  __syncthreads();
  // W doubling: w_{t+2^k} = (R^T)^{2^k} w_t
  for (int k = 0; k < 5; ++k) {
    int cnt = 1 << k;
    for (int t = wv; t < cnt; t += 4) {
      float accv = 0.f;
#pragma unroll
      for (int k4 = 0; k4 < 16; ++k4) {
        int jM = (k4 << 2) ^ (lane & 28);
        float4 mv = *(const float4*)&Pc[(lane << 6) + jM];
        float4 wvv = *(const float4*)&Wt[t * 68 + (k4 << 2)];
        accv += mv.x * wvv.x + mv.y * wvv.y + mv.z * wvv.z + mv.w * wvv.w;
      }
      Wt[(t + cnt) * 68 + lane] = accv;
    }
    if (k < 4) {
      mm64(Pn, Pc, Pc, b0, 0.f, 0.f, 0, tid);
      float* t2 = Pc; Pc = Pn; Pn = t2;
    } else {
      __syncthreads();
    }
  }

  // K[64t'+t] = w_t' . v_t  -> K in Pn (dead matrix buffer)
  float* K = Pn;
  for (int x = tid; x < 2048; x += 256) {
    int tp = x >> 6, t = x & 63;
    float dot = 0.f;
#pragma unroll
    for (int i4 = 0; i4 < 64; i4 += 4) {
      float4 wvv = *(const float4*)&Wt[tp * 68 + i4];
      float4 vvv = *(const float4*)&Vt[t * 68 + i4];
      dot += wvv.x * vvv.x + wvv.y * vvv.y + wvv.z * vvv.z + wvv.w * vvv.w;
    }
    K[x] = dot;
  }
  __syncthreads();

  // split (with D folded at x=2047) -> kh/kl; suffix-energy partials
  unsigned short* kh = (unsigned short*)Pc;
  unsigned short* kl = kh + 2192;
  float* ss = (float*)(kh + 4400);
  const float D = D_skip[0];
  for (int x = tid; x < 2192; x += 256) {
    float v = 0.f;
    if (x < 2048) { v = K[x]; if (x == 2047) v += D; }
    unsigned h = rne_bf16(v);
    float hf2 = __uint_as_float(h << 16);
    unsigned l = rne_bf16(v - hf2);
    kh[x] = (unsigned short)h;
    kl[x] = (unsigned short)l;
  }
  {
    float ssum = 0.f;
#pragma unroll
    for (int q = 0; q < 8; ++q) {
      int x = (tid << 3) + q;
      float v = K[x];
      if (x == 2047) v += D;
      ssum += v * v;
    }
    ss[tid] = ssum;
  }
  __syncthreads();

  // ring tables: rg[e] = krev16[e..e+7]
  for (int e = tid; e < 2176; e += 256) {
    unsigned ph[4], pl[4];
#pragma unroll
    for (int q2 = 0; q2 < 4; ++q2) {
      ph[q2] = (unsigned)kh[e + 2 * q2] | ((unsigned)kh[e + 2 * q2 + 1] << 16);
      pl[q2] = (unsigned)kl[e + 2 * q2] | ((unsigned)kl[e + 2 * q2 + 1] << 16);
    }
    rg_hi[e] = make_uint4(ph[0], ph[1], ph[2], ph[3]);
    rg_lo[e] = make_uint4(pl[0], pl[1], pl[2], pl[3]);
  }
  if (tid == 0) {
    float accq = 0.f;
    int xt = 0;
    for (int jc = 255; jc >= 0; --jc) {
      float na = accq + ss[jc];
      if (na > 4e-8f) { xt = (jc + 1) << 3; break; }
      accq = na;
    }
    wsi[0] = 2048 - xt;
  }
}

// ---------------------------------------------------------------------------
// conv kernel
// ---------------------------------------------------------------------------
__device__ __forceinline__ void load_bfrag(short8* bf, const uint4* ubf,
                                           const float* u, int use_ubf, int b,
                                           int kt, int h0, int wn, int lane) {
  if (use_ubf) {
    const short8* base = (const short8*)(ubf + ((((b << 6) | kt) << 11) |
                                               (((h0 >> 4) + (wn << 2)) << 6) |
                                               lane));
#pragma unroll
    for (int j = 0; j < 4; ++j) bf[j] = base[j << 6];
  } else {
    int gg = lane >> 4, hm = lane & 15;
#pragma unroll
    for (int j = 0; j < 4; ++j) {
      const float* src = u + ((((b << 11) + (kt << 5) + (gg << 3)) << 9) + h0 +
                              (((wn << 2) + j) << 4) + hm);
      unsigned pk[4];
#pragma unroll
      for (int q = 0; q < 4; ++q) {
        unsigned lo = rne_bf16(src[q << 10]);
        unsigned hi = rne_bf16(src[(q << 10) + 512]);
        pk[q] = lo | (hi << 16);
      }
      uint4 vv = make_uint4(pk[0], pk[1], pk[2], pk[3]);
      bf[j] = __builtin_bit_cast(short8, vv);
    }
  }
}

__global__ __launch_bounds__(256) void conv_kernel(
    const float* __restrict__ u, const uint4* __restrict__ rg_hi,
    const uint4* __restrict__ rg_lo, const uint4* __restrict__ ubf,
    const int* __restrict__ wsi, float* __restrict__ y, int use_ubf) {
  __shared__ __align__(16) unsigned ringh[1024], ringl[1024];  // 256x16B each
  const int tid = threadIdx.x;
  const int bid = blockIdx.x;
  const int b = bid >> 5;
  const int bn = bid & 3;
  const int pr = (bid >> 2) & 7;
  const int h0 = bn << 7;
  const int lane = tid & 63, w = tid >> 6;
  const int wm = w & 1, wn = w >> 1;
  const int g = lane >> 4, m = lane & 15;
  const int D_lo = wsi[0];

  for (int tile = 0; tile < 2; ++tile) {
    const int bm = tile ? pr : 15 - pr;
    const int l0 = bm << 7;
    const int e0 = 1920 - l0;
    const int ktiles = 4 * bm + 4;
    int kt_lim = ((l0 + 127 - D_lo) >> 5) + 1;
    if (kt_lim < 0) kt_lim = 0;
    if (kt_lim > ktiles) kt_lim = ktiles;

    __syncthreads();  // previous tile's ring reads complete
    for (int tsk = tid; tsk < 432; tsk += 256) {
      int isLo = tsk >= 216;
      int e = e0 + (isLo ? tsk - 216 : tsk);
      if (e <= 2175) {
        uint4 v = isLo ? rg_lo[e] : rg_hi[e];
        ((uint4*)(isLo ? ringl : ringh))[e & 255] = v;
      }
    }

    f32x4 acc[4][4];
#pragma unroll
    for (int i = 0; i < 4; ++i)
#pragma unroll
      for (int j = 0; j < 4; ++j) acc[i][j] = (f32x4){0.f, 0.f, 0.f, 0.f};

    short8 bcur[4];
    if (kt_lim > 0) load_bfrag(bcur, ubf, u, use_ubf, b, 0, h0, wn, lane);

    for (int kt = 0; kt < kt_lim; ++kt) {
      __syncthreads();  // ring writes visible
      // top-up read (for chunk kt+3's window) -- into registers
      uint4 tv;
      bool tdo = false;
      int tslot = 0;
      const bool tlo = (tid >= 32);
      if (tid < 64) {
        int te = e0 + 216 + (kt << 5) + (tid & 31);
        if (te <= 2175) {
          tv = tlo ? rg_lo[te] : rg_hi[te];
          tdo = true;
          tslot = te & 255;
        }
      }
      // A-fragments from ring
      const int ebase = 2047 - l0 + (kt << 5) - (wm << 6) - m + (g << 3);
      short8 ah[4], al[4];
#pragma unroll
      for (int i = 0; i < 4; ++i) {
        int slot = (ebase - (i << 4)) & 255;
        ah[i] = ((const short8*)ringh)[slot];
        al[i] = ((const short8*)ringl)[slot];
      }
      // prefetch next b-frags
      short8 bnx[4];
      if (kt + 1 < kt_lim)
        load_bfrag(bnx, ubf, u, use_ubf, b, kt + 1, h0, wn, lane);
#pragma unroll
      for (int i = 0; i < 4; ++i)
#pragma unroll
        for (int j = 0; j < 4; ++j) {
          acc[i][j] = __builtin_amdgcn_mfma_f32_16x16x32_bf16(ah[i], bcur[j],
                                                              acc[i][j], 0, 0, 0);
          acc[i][j] = __builtin_amdgcn_mfma_f32_16x16x32_bf16(al[i], bcur[j],
                                                              acc[i][j], 0, 0, 0);
        }
      if (tdo) ((uint4*)(tlo ? ringl : ringh))[tslot] = tv;
      if (kt + 1 < kt_lim) {
#pragma unroll
        for (int j = 0; j < 4; ++j) bcur[j] = bnx[j];
      }
    }

    // epilogue: y = acc  (D folded into K); C/D: col=lane&15, row=g*4+reg
#pragma unroll
    for (int i = 0; i < 4; ++i)
#pragma unroll
      for (int j = 0; j < 4; ++j) {
        int l = l0 + (wm << 6) + (i << 4) + (g << 2);
        int h = h0 + (((wn << 2) + j) << 4) + m;
        int off = (((b << 11) + l) << 9) + h;
#pragma unroll
        for (int r = 0; r < 4; ++r) y[off + (r << 9)] = acc[i][j][r];
      }
  }
}

extern "C" void kernel_launch(void* const* d_in, const int* in_sizes, int n_in,
                              void* d_out, int out_size, void* d_ws,
                              size_t ws_size, hipStream_t stream) {
  (void)in_sizes; (void)n_in; (void)out_size;
  const float* u = (const float*)d_in[0];
  const float* B_ssm = (const float*)d_in[1];
  const float* C_ssm = (const float*)d_in[2];
  const float* D_skip = (const float*)d_in[3];
  const float* log_dt = (const float*)d_in[4];
  float* y = (float*)d_out;

  const size_t UBF_BYTES = (size_t)16 * 64 * 2048 * 16;  // 32 MB
  const size_t RG_BYTES = (size_t)2176 * 16 * 2 + 256;
  int use_ubf = (ws_size >= UBF_BYTES + RG_BYTES) ? 1 : 0;
  char* wsb = (char*)d_ws;
  uint4* ubf = (uint4*)wsb;
  uint4* rg_hi = use_ubf ? (uint4*)(wsb + UBF_BYTES) : (uint4*)wsb;
  uint4* rg_lo = rg_hi + 2176;
  int* wsi = (int*)(rg_lo + 2176);

  prep_quant<<<use_ubf ? 2049 : 1, 256, 0, stream>>>(
      u, B_ssm, C_ssm, D_skip, log_dt, rg_hi, rg_lo, wsi, ubf);
  conv_kernel<<<512, 256, 0, stream>>>(u, rg_hi, rg_lo, ubf, wsi, y, use_ubf);
}

// Round 4
// 218.359 us; speedup vs baseline: 1.1297x; 1.0657x over previous
//
#include <hip/hip_runtime.h>
#include <math.h>

// ---------------------------------------------------------------------------
// S4 conv:  y[b,l,h] = sum_{t<=l} K[2047-(l-t)]*u[t,h] + D*u[l,h]
// prep_quant (block 0): expm(dt*A) via order-9 Taylor + scaling/squaring;
//   B_bar fp64 solve; log-depth doubling scans -> K; emits pre-shifted
//   ring tables rg_hi/rg_lo (16B groups krev16[e..e+7]) + cutoff.
// prep_quant (blocks 1..2048): quantize u -> bf16 B-fragment layout (ubf).
// conv (512 blocks): 128x128 bf16 MFMA, 2-product (Khi,Klo).
//
// R5->R6: block-0 serial 64^3 chain moved to MATRIX CORES.
//   - every 64x64x64 product = bf16 hi/lo split 3-product MFMA
//     (16x16x32), operands kept in LDS as XOR-swizzled row-form AND
//     col-form splits; both orientations (C and C^T via swapped operands)
//     computed so both forms are written with ds_write_b64 strips.
//   - chain tracks E = expm - I (Taylor c0 dropped; squaring E'=E^2+2E via
//     the addG path) so the B_bar solve has NO near-identity cancellation.
//   - W-scan runs column-form on untransposed powers M_7..M_10 (transpose
//     step deleted); Vt XOR-swizzled stride-64, Wt plain stride-64.
//   LDS: b0 = X fp32 -> Bl -> Vt ; b1 = X2col -> E fp32 -> Wt ;
//        b2 = row-splits -> kh/kl/ss ; b3 = col-splits -> K.
// (R6 resubmit: round-3 bench died on container acquisition, not the kernel.)
// ---------------------------------------------------------------------------

typedef short short8 __attribute__((ext_vector_type(8)));
typedef short short4v __attribute__((ext_vector_type(4)));
typedef float f32x4 __attribute__((ext_vector_type(4)));

#define SWMASK 28
__device__ __forceinline__ int swz(int r, int c) {
  return (r << 6) + (c ^ (r & SWMASK));
}
__device__ __forceinline__ float Aval(int i, int j) {
  if (i > j)  return -(float)(sqrt(2.0 * i + 1.0) * sqrt(2.0 * j + 1.0));
  if (i == j) return -(float)(i + 1);
  return 0.0f;
}
__device__ __forceinline__ unsigned rne_bf16(float x) {
  unsigned u = __float_as_uint(x);
  return (u + 0x7FFFu + ((u >> 16) & 1u)) >> 16;
}
__device__ __forceinline__ float invfact(int k) {
  switch (k) {
    case 0: return 1.0f;            case 1: return 1.0f;
    case 2: return 0.5f;            case 3: return (float)(1.0/6.0);
    case 4: return (float)(1.0/24.0);       case 5: return (float)(1.0/120.0);
    case 6: return (float)(1.0/720.0);      case 7: return (float)(1.0/5040.0);
    case 8: return (float)(1.0/40320.0);    default: return (float)(1.0/362880.0);
  }
}
// split-buffer addressing: ushort[64 rows][64 k], 16B slots XOR-swizzled.
// slotU(row,kg) = ushort index of the 8-element group kg (=k/8) of `row`.
__device__ __forceinline__ int slotU(int row, int kg) {
  return (row << 6) + ((kg ^ (row & 7)) << 3);
}
__device__ __forceinline__ float bf2f(unsigned short s) {
  return __uint_as_float(((unsigned)s) << 16);
}
__device__ __forceinline__ unsigned short bfh(float x) {
  return (unsigned short)rne_bf16(x);
}
__device__ __forceinline__ unsigned short bfl(float x, unsigned short h) {
  return (unsigned short)rne_bf16(x - __uint_as_float(((unsigned)h) << 16));
}

// C = L*R (+ cI*I + cX*Xg). rowL* = row-form splits of L, colR* = col-form
// splits of R. Writes (optional): col-form of C (oCol*), row-form of C
// (oRow*), fp32 swizzled C (oF32). Frag layouts match conv kernel:
// A/B frag: lane=(g=lane>>4, m=lane&15) holds 8 consecutive k of row/col m,
// k base = 32*kt + 8*g.  C/D: row = 4g+r, col = m (per 16x16 tile).
// 2 barriers: after compute (before overwriting splits), after writes.
__device__ __forceinline__ void mmMFMA(
    const unsigned short* rowLh, const unsigned short* rowLl,
    const unsigned short* colRh, const unsigned short* colRl,
    unsigned short* oColH, unsigned short* oColL,
    unsigned short* oRowH, unsigned short* oRowL,
    float* oF32, const float* Xg, float cI, float cX, int tid) {
  const int lane = tid & 63, w = tid >> 6;
  const int g = lane >> 4, m = lane & 15;
  const bool doN = (oColH != nullptr) || (oF32 != nullptr);
  const bool doT = (oRowH != nullptr);
  f32x4 an[4], at[4];

  if (doN) {  // normal: acc_n[nt][r] = C[16w+4g+r][16nt+m]
    short8 ah[2], al[2];
#pragma unroll
    for (int kt = 0; kt < 2; ++kt) {
      ah[kt] = *(const short8*)&rowLh[slotU(16 * w + m, 4 * kt + g)];
      al[kt] = *(const short8*)&rowLl[slotU(16 * w + m, 4 * kt + g)];
    }
#pragma unroll
    for (int nt = 0; nt < 4; ++nt) {
      an[nt] = (f32x4){0.f, 0.f, 0.f, 0.f};
#pragma unroll
      for (int kt = 0; kt < 2; ++kt) {
        short8 bh = *(const short8*)&colRh[slotU(16 * nt + m, 4 * kt + g)];
        short8 bl = *(const short8*)&colRl[slotU(16 * nt + m, 4 * kt + g)];
        an[nt] = __builtin_amdgcn_mfma_f32_16x16x32_bf16(ah[kt], bh, an[nt], 0, 0, 0);
        an[nt] = __builtin_amdgcn_mfma_f32_16x16x32_bf16(ah[kt], bl, an[nt], 0, 0, 0);
        an[nt] = __builtin_amdgcn_mfma_f32_16x16x32_bf16(al[kt], bh, an[nt], 0, 0, 0);
      }
      if (Xg) {
#pragma unroll
        for (int r = 0; r < 4; ++r) {
          int rc = 16 * w + 4 * g + r, cc = 16 * nt + m;
          float gv = cX * Xg[(rc << 6) + (cc ^ (rc & 28))];
          if (rc == cc) gv += cI;
          an[nt][r] += gv;
        }
      }
    }
  }
  if (doT) {  // transposed: acc_t[nt][r] = C[16nt+m][16w+4g+r]
    short8 ah[2], al[2];
#pragma unroll
    for (int kt = 0; kt < 2; ++kt) {
      ah[kt] = *(const short8*)&colRh[slotU(16 * w + m, 4 * kt + g)];
      al[kt] = *(const short8*)&colRl[slotU(16 * w + m, 4 * kt + g)];
    }
#pragma unroll
    for (int nt = 0; nt < 4; ++nt) {
      at[nt] = (f32x4){0.f, 0.f, 0.f, 0.f};
#pragma unroll
      for (int kt = 0; kt < 2; ++kt) {
        short8 bh = *(const short8*)&rowLh[slotU(16 * nt + m, 4 * kt + g)];
        short8 bl = *(const short8*)&rowLl[slotU(16 * nt + m, 4 * kt + g)];
        at[nt] = __builtin_amdgcn_mfma_f32_16x16x32_bf16(ah[kt], bh, at[nt], 0, 0, 0);
        at[nt] = __builtin_amdgcn_mfma_f32_16x16x32_bf16(ah[kt], bl, at[nt], 0, 0, 0);
        at[nt] = __builtin_amdgcn_mfma_f32_16x16x32_bf16(al[kt], bh, at[nt], 0, 0, 0);
      }
      if (Xg) {
        int rc = 16 * nt + m;
        int cb = 16 * w + 4 * g;
        f32x4 xv = *(const f32x4*)&Xg[(rc << 6) + (cb ^ (rc & 28))];
#pragma unroll
        for (int r = 0; r < 4; ++r) {
          float gv = cX * xv[r];
          if (rc == cb + r) gv += cI;
          at[nt][r] += gv;
        }
      }
    }
  }
  __syncthreads();  // all split reads done -> safe to overwrite splits
  const int k0 = 16 * w + 4 * g;
  if (doN) {
#pragma unroll
    for (int nt = 0; nt < 4; ++nt) {
      if (oColH) {
        short4v h4, l4;
#pragma unroll
        for (int r = 0; r < 4; ++r) {
          unsigned short h = bfh(an[nt][r]);
          h4[r] = (short)h;
          l4[r] = (short)bfl(an[nt][r], h);
        }
        int s = slotU(16 * nt + m, k0 >> 3) + (k0 & 7);
        *(short4v*)&oColH[s] = h4;
        *(short4v*)&oColL[s] = l4;
      }
      if (oF32) {
#pragma unroll
        for (int r = 0; r < 4; ++r) {
          int rc = k0 + r;
          oF32[(rc << 6) + ((16 * nt + m) ^ (rc & 28))] = an[nt][r];
        }
      }
    }
  }
  if (doT) {
#pragma unroll
    for (int nt = 0; nt < 4; ++nt) {
      short4v h4, l4;
#pragma unroll
      for (int r = 0; r < 4; ++r) {
        unsigned short h = bfh(at[nt][r]);
        h4[r] = (short)h;
        l4[r] = (short)bfl(at[nt][r], h);
      }
      int s = slotU(16 * nt + m, k0 >> 3) + (k0 & 7);
      *(short4v*)&oRowH[s] = h4;
      *(short4v*)&oRowL[s] = l4;
    }
  }
  __syncthreads();
}

__global__ __launch_bounds__(256) void prep_quant(
    const float* __restrict__ u, const float* __restrict__ B_ssm,
    const float* __restrict__ C_ssm, const float* __restrict__ D_skip,
    const float* __restrict__ log_dt, uint4* __restrict__ rg_hi,
    uint4* __restrict__ rg_lo, int* __restrict__ wsi,
    uint4* __restrict__ ubf) {
  __shared__ __align__(16) float smem[16384];  // 64 KB
  const int tid = threadIdx.x;

  if (blockIdx.x != 0) {
    // ---------------- u-quant block: (b, tc, half) -> ubf ----------------
    int q = blockIdx.x - 1;                 // 0..2047
    int b = q >> 7, rem = q & 127;
    int tc = rem >> 1, hf = rem & 1;
    int t0 = (tc << 5) + (hf << 4);
    float* S = smem;                        // [16][520]
#pragma unroll
    for (int r = 0; r < 8; ++r) {
      int s = tid + (r << 8);               // 2048 float4-slots
      int row = s >> 7, c4 = (s & 127) << 2;
      float4 v = *(const float4*)(u + ((((b << 11) + t0 + row) << 9) + c4));
      *(float4*)&S[row * 520 + c4] = v;
    }
    __syncthreads();
#pragma unroll
    for (int r = 0; r < 4; ++r) {
      int gidx = tid + (r << 8);            // 0..1023
      int jnG = gidx >> 5;                  // 0..31
      int gl = (gidx >> 4) & 1;
      int hm = gidx & 15;
      int gg = (hf << 1) | gl;
      int h = (jnG << 4) + hm;
      int tb = gl << 3;
      unsigned pk[4];
#pragma unroll
      for (int q2 = 0; q2 < 4; ++q2) {
        unsigned lo = rne_bf16(S[(tb + 2 * q2) * 520 + h]);
        unsigned hi = rne_bf16(S[(tb + 2 * q2 + 1) * 520 + h]);
        pk[q2] = lo | (hi << 16);
      }
      ubf[(((b << 6) | tc) << 11) | (jnG << 6) | (gg << 4) | hm] =
          make_uint4(pk[0], pk[1], pk[2], pk[3]);
    }
    return;
  }

  // ---------------- prep block ----------------
  float* b0 = smem;
  float* b1 = smem + 4096;
  float* b2 = smem + 8192;
  float* b3 = smem + 12288;
  unsigned short* RH = (unsigned short*)b2;   // row-form hi
  unsigned short* RL = RH + 4096;             // row-form lo
  unsigned short* CH = (unsigned short*)b3;   // col-form hi
  unsigned short* CL = CH + 4096;             // col-form lo
  unsigned short* X2H = (unsigned short*)b1;  // X2 col-form hi
  unsigned short* X2L = X2H + 4096;
  const int lane = tid & 63, wv = tid >> 6;
  const float dtf = expf(log_dt[0]);

  // ||A||_1 column sums: cs[j] = (j+1) + P_j * sum_{i>j} P_i
  if (tid < 64) {
    double p = sqrt(2.0 * tid + 1.0);
    double s = p;
#pragma unroll
    for (int off = 1; off < 64; off <<= 1) {
      double t = __shfl_down(s, off, 64);
      if (tid + off < 64) s += t;
    }
    b2[tid] = (float)((tid + 1.0) + p * (s - p));
  }
  __syncthreads();
  float maxc = 0.f;
  for (int j = 0; j < 64; ++j) maxc = fmaxf(maxc, b2[j]);
  int iE;
  frexpf(dtf * maxc, &iE);
  int sExp = iE > 0 ? iE : 0;  // eta <= 1.0; order-9 Taylor err ~7e-7
  const float scale = ldexpf(dtf, -sExp);
  __syncthreads();

  // ---- X init: fp32 (b0, swizzled) + row-splits (b2) + col-splits (b3)
  const int r0i = (tid & 15) << 2, c0i = (tid >> 4) << 2;
  float xv[4][4];
  unsigned short xh[4][4], xl[4][4];
#pragma unroll
  for (int i = 0; i < 4; ++i)
#pragma unroll
    for (int j = 0; j < 4; ++j) {
      float x = scale * Aval(r0i + i, c0i + j);
      xv[i][j] = x;
      xh[i][j] = bfh(x);
      xl[i][j] = bfl(x, xh[i][j]);
      b0[swz(r0i + i, c0i + j)] = x;
    }
#pragma unroll
  for (int i = 0; i < 4; ++i) {  // row-form [r0i+i][c0i..c0i+3]
    short4v h4, l4;
#pragma unroll
    for (int j = 0; j < 4; ++j) { h4[j] = (short)xh[i][j]; l4[j] = (short)xl[i][j]; }
    int s = slotU(r0i + i, c0i >> 3) + (c0i & 7);
    *(short4v*)&RH[s] = h4;
    *(short4v*)&RL[s] = l4;
  }
#pragma unroll
  for (int j = 0; j < 4; ++j) {  // col-form [c0i+j][r0i..r0i+3]
    short4v h4, l4;
#pragma unroll
    for (int i = 0; i < 4; ++i) { h4[i] = (short)xh[i][j]; l4[i] = (short)xl[i][j]; }
    int s = slotU(c0i + j, r0i >> 3) + (r0i & 7);
    *(short4v*)&CH[s] = h4;
    *(short4v*)&CL[s] = l4;
  }
  __syncthreads();

  // X2 = X*X -> col-form only (b1)
  mmMFMA(RH, RL, CH, CL, X2H, X2L, nullptr, nullptr, nullptr, nullptr,
         0.f, 0.f, tid);

  // G = c8*I + c9*X -> row-form (b2); X-row dead after X2's reads.
#pragma unroll
  for (int i = 0; i < 4; ++i) {
    short4v h4, l4;
#pragma unroll
    for (int j = 0; j < 4; ++j) {
      float gv = invfact(9) * xv[i][j];
      if (r0i + i == c0i + j) gv += invfact(8);
      unsigned short h = bfh(gv);
      h4[j] = (short)h;
      l4[j] = (short)bfl(gv, h);
    }
    int s = slotU(r0i + i, c0i >> 3) + (c0i & 7);
    *(short4v*)&RH[s] = h4;
    *(short4v*)&RL[s] = l4;
  }
  __syncthreads();

  // Horner m=3..1: P = P*X2 + (c2m*I + c2m+1*X) -> row-form only
  for (int mq = 3; mq >= 1; --mq)
    mmMFMA(RH, RL, X2H, X2L, nullptr, nullptr, RH, RL, nullptr, b0,
           invfact(2 * mq), invfact(2 * mq + 1), tid);
  // last Horner (m=0), E-form: E = P*X2 + 0*I + 1*X  (= e^X - I)
  // -> row (b2), col (b3), fp32 E (b1; overwrites X2col after reads)
  mmMFMA(RH, RL, X2H, X2L, CH, CL, RH, RL, b1, b0, 0.f, 1.f, tid);

  // exp-squarings in E-form: E' = E*E + 2*E  (Xg = old E fp32 in b1)
  for (int q = 0; q < sExp; ++q)
    mmMFMA(RH, RL, CH, CL, CH, CL, RH, RL, b1, b1, 0.f, 2.f, tid);

  // ---- diag fixup (M_0 = I + E in the splits) + load Bl; X fp32 dead.
  float* Bl = b0 + 64;
  if (tid < 64) {
    Bl[tid] = B_ssm[tid];
    int d = tid;
    float x = b1[(d << 6) + (d ^ (d & 28))] + 1.0f;
    unsigned short h = bfh(x), l = bfl(x, h);
    int s = slotU(d, d >> 3) + (d & 7);
    RH[s] = h; RL[s] = l; CH[s] = h; CL[s] = l;
  }
  __syncthreads();

  // B_bar: solve A x = E*B  (E = A_bar - I fp32 in b1; no cancellation)
  if (tid < 64) {
    int i = tid;
    double accd = 0.0;
#pragma unroll
    for (int k4 = 0; k4 < 16; ++k4) {
      int jM = (k4 << 2) ^ (i & 28);
      float4 mv = *(const float4*)&b1[(i << 6) + jM];
      float4 bv = *(const float4*)&Bl[k4 << 2];
      accd += (double)mv.x * bv.x + (double)mv.y * bv.y +
              (double)mv.z * bv.z + (double)mv.w * bv.w;
    }
    double xvv = 0.0;
    for (int j = 0; j < 64; ++j) {
      if (i == j) xvv = accd / (double)Aval(j, j);
      double xj = __shfl(xvv, j, 64);
      if (i > j) accd -= (double)Aval(i, j) * xj;
    }
    b0[i] = (float)xvv;  // Vt[0] = B_bar  (Vt: stride 64, XOR-swizzled)
  }
  __syncthreads();

  // V doubling: v_{t+2^k} = M_k v_t (row-form reads), then square.
  for (int k = 0; k < 6; ++k) {
    int cnt = 1 << k;
    for (int t = wv; t < cnt; t += 4) {
      float accv = 0.f;
#pragma unroll
      for (int kg = 0; kg < 8; ++kg) {
        short8 mh = *(const short8*)&RH[slotU(lane, kg)];
        short8 ml = *(const short8*)&RL[slotU(lane, kg)];
        f32x4 v0 = *(const f32x4*)&b0[(t << 6) + ((kg << 3) ^ (t & 28))];
        f32x4 v1 = *(const f32x4*)&b0[(t << 6) + (((kg << 3) + 4) ^ (t & 28))];
#pragma unroll
        for (int j = 0; j < 4; ++j)
          accv += (bf2f((unsigned short)mh[j]) + bf2f((unsigned short)ml[j])) * v0[j];
#pragma unroll
        for (int j = 0; j < 4; ++j)
          accv += (bf2f((unsigned short)mh[4 + j]) + bf2f((unsigned short)ml[4 + j])) * v1[j];
      }
      int td = t + cnt;
      b0[(td << 6) + (lane ^ (td & 28))] = accv;
    }
    // square M_k -> M_{k+1} (mmMFMA's first barrier covers matvec reads)
    mmMFMA(RH, RL, CH, CL, CH, CL, RH, RL, nullptr, nullptr, 0.f, 0.f, tid);
  }

  // W init: w_0 = C  (Wt: b1, plain stride 64; E fp32 dead after solve)
  if (tid < 64) b1[tid] = C_ssm[tid];
  __syncthreads();
  // W doubling (column-form, untransposed): w_{t+2^k}[i] = sum_j w_t[j] M[j][i]
  for (int k = 0; k < 5; ++k) {
    int cnt = 1 << k;
    for (int t = wv; t < cnt; t += 4) {
      float accv = 0.f;
#pragma unroll
      for (int kg = 0; kg < 8; ++kg) {
        short8 ch8 = *(const short8*)&CH[slotU(lane, kg)];
        short8 cl8 = *(const short8*)&CL[slotU(lane, kg)];
        f32x4 w0 = *(const f32x4*)&b1[(t << 6) + (kg << 3)];
        f32x4 w1 = *(const f32x4*)&b1[(t << 6) + (kg << 3) + 4];
#pragma unroll
        for (int j = 0; j < 4; ++j)
          accv += (bf2f((unsigned short)ch8[j]) + bf2f((unsigned short)cl8[j])) * w0[j];
#pragma unroll
        for (int j = 0; j < 4; ++j)
          accv += (bf2f((unsigned short)ch8[4 + j]) + bf2f((unsigned short)cl8[4 + j])) * w1[j];
      }
      b1[((t + cnt) << 6) + lane] = accv;
    }
    if (k < 3) {
      mmMFMA(RH, RL, CH, CL, CH, CL, RH, RL, nullptr, nullptr, 0.f, 0.f, tid);
    } else if (k == 3) {
      // M_10 only consumed col-form by level-4 matvec
      mmMFMA(RH, RL, CH, CL, CH, CL, nullptr, nullptr, nullptr, nullptr,
             0.f, 0.f, tid);
    } else {
      __syncthreads();  // after last matvec, before K overwrites b3
    }
  }

  // K[64t'+t] = w_t' . v_t  -> K in b3 (col-splits dead)
  float* K = b3;
  for (int x = tid; x < 2048; x += 256) {
    int tp = x >> 6, t = x & 63;
    float dot = 0.f;
#pragma unroll
    for (int i4 = 0; i4 < 64; i4 += 4) {
      f32x4 wv4 = *(const f32x4*)&b1[(tp << 6) + i4];
      f32x4 vv4 = *(const f32x4*)&b0[(t << 6) + (i4 ^ (t & 28))];
      dot += wv4[0] * vv4[0] + wv4[1] * vv4[1] + wv4[2] * vv4[2] +
             wv4[3] * vv4[3];
    }
    K[x] = dot;
  }
  __syncthreads();

  // split (with D folded at x=2047) -> kh/kl (b2); suffix-energy partials
  unsigned short* kh = (unsigned short*)b2;
  unsigned short* kl = kh + 2192;
  float* ss = (float*)(kh + 4400);
  const float D = D_skip[0];
  for (int x = tid; x < 2192; x += 256) {
    float v = 0.f;
    if (x < 2048) { v = K[x]; if (x == 2047) v += D; }
    unsigned h = rne_bf16(v);
    float hf2 = __uint_as_float(h << 16);
    unsigned l = rne_bf16(v - hf2);
    kh[x] = (unsigned short)h;
    kl[x] = (unsigned short)l;
  }
  {
    float ssum = 0.f;
#pragma unroll
    for (int q = 0; q < 8; ++q) {
      int x = (tid << 3) + q;
      float v = K[x];
      if (x == 2047) v += D;
      ssum += v * v;
    }
    ss[tid] = ssum;
  }
  __syncthreads();

  // ring tables: rg[e] = krev16[e..e+7]
  for (int e = tid; e < 2176; e += 256) {
    unsigned ph[4], pl[4];
#pragma unroll
    for (int q2 = 0; q2 < 4; ++q2) {
      ph[q2] = (unsigned)kh[e + 2 * q2] | ((unsigned)kh[e + 2 * q2 + 1] << 16);
      pl[q2] = (unsigned)kl[e + 2 * q2] | ((unsigned)kl[e + 2 * q2 + 1] << 16);
    }
    rg_hi[e] = make_uint4(ph[0], ph[1], ph[2], ph[3]);
    rg_lo[e] = make_uint4(pl[0], pl[1], pl[2], pl[3]);
  }
  if (tid == 0) {
    float accq = 0.f;
    int xt = 0;
    for (int jc = 255; jc >= 0; --jc) {
      float na = accq + ss[jc];
      if (na > 4e-8f) { xt = (jc + 1) << 3; break; }
      accq = na;
    }
    wsi[0] = 2048 - xt;
  }
}

// ---------------------------------------------------------------------------
// conv kernel (unchanged)
// ---------------------------------------------------------------------------
__device__ __forceinline__ void load_bfrag(short8* bf, const uint4* ubf,
                                           const float* u, int use_ubf, int b,
                                           int kt, int h0, int wn, int lane) {
  if (use_ubf) {
    const short8* base = (const short8*)(ubf + ((((b << 6) | kt) << 11) |
                                               (((h0 >> 4) + (wn << 2)) << 6) |
                                               lane));
#pragma unroll
    for (int j = 0; j < 4; ++j) bf[j] = base[j << 6];
  } else {
    int gg = lane >> 4, hm = lane & 15;
#pragma unroll
    for (int j = 0; j < 4; ++j) {
      const float* src = u + ((((b << 11) + (kt << 5) + (gg << 3)) << 9) + h0 +
                              (((wn << 2) + j) << 4) + hm);
      unsigned pk[4];
#pragma unroll
      for (int q = 0; q < 4; ++q) {
        unsigned lo = rne_bf16(src[q << 10]);
        unsigned hi = rne_bf16(src[(q << 10) + 512]);
        pk[q] = lo | (hi << 16);
      }
      uint4 vv = make_uint4(pk[0], pk[1], pk[2], pk[3]);
      bf[j] = __builtin_bit_cast(short8, vv);
    }
  }
}

__global__ __launch_bounds__(256) void conv_kernel(
    const float* __restrict__ u, const uint4* __restrict__ rg_hi,
    const uint4* __restrict__ rg_lo, const uint4* __restrict__ ubf,
    const int* __restrict__ wsi, float* __restrict__ y, int use_ubf) {
  __shared__ __align__(16) unsigned ringh[1024], ringl[1024];  // 256x16B each
  const int tid = threadIdx.x;
  const int bid = blockIdx.x;
  const int b = bid >> 5;
  const int bn = bid & 3;
  const int pr = (bid >> 2) & 7;
  const int h0 = bn << 7;
  const int lane = tid & 63, w = tid >> 6;
  const int wm = w & 1, wn = w >> 1;
  const int g = lane >> 4, m = lane & 15;
  const int D_lo = wsi[0];

  for (int tile = 0; tile < 2; ++tile) {
    const int bm = tile ? pr : 15 - pr;
    const int l0 = bm << 7;
    const int e0 = 1920 - l0;
    const int ktiles = 4 * bm + 4;
    int kt_lim = ((l0 + 127 - D_lo) >> 5) + 1;
    if (kt_lim < 0) kt_lim = 0;
    if (kt_lim > ktiles) kt_lim = ktiles;

    __syncthreads();  // previous tile's ring reads complete
    for (int tsk = tid; tsk < 432; tsk += 256) {
      int isLo = tsk >= 216;
      int e = e0 + (isLo ? tsk - 216 : tsk);
      if (e <= 2175) {
        uint4 v = isLo ? rg_lo[e] : rg_hi[e];
        ((uint4*)(isLo ? ringl : ringh))[e & 255] = v;
      }
    }

    f32x4 acc[4][4];
#pragma unroll
    for (int i = 0; i < 4; ++i)
#pragma unroll
      for (int j = 0; j < 4; ++j) acc[i][j] = (f32x4){0.f, 0.f, 0.f, 0.f};

    short8 bcur[4];
    if (kt_lim > 0) load_bfrag(bcur, ubf, u, use_ubf, b, 0, h0, wn, lane);

    for (int kt = 0; kt < kt_lim; ++kt) {
      __syncthreads();  // ring writes visible
      uint4 tv;
      bool tdo = false;
      int tslot = 0;
      const bool tlo = (tid >= 32);
      if (tid < 64) {
        int te = e0 + 216 + (kt << 5) + (tid & 31);
        if (te <= 2175) {
          tv = tlo ? rg_lo[te] : rg_hi[te];
          tdo = true;
          tslot = te & 255;
        }
      }
      const int ebase = 2047 - l0 + (kt << 5) - (wm << 6) - m + (g << 3);
      short8 ah[4], al[4];
#pragma unroll
      for (int i = 0; i < 4; ++i) {
        int slot = (ebase - (i << 4)) & 255;
        ah[i] = ((const short8*)ringh)[slot];
        al[i] = ((const short8*)ringl)[slot];
      }
      short8 bnx[4];
      if (kt + 1 < kt_lim)
        load_bfrag(bnx, ubf, u, use_ubf, b, kt + 1, h0, wn, lane);
#pragma unroll
      for (int i = 0; i < 4; ++i)
#pragma unroll
        for (int j = 0; j < 4; ++j) {
          acc[i][j] = __builtin_amdgcn_mfma_f32_16x16x32_bf16(ah[i], bcur[j],
                                                              acc[i][j], 0, 0, 0);
          acc[i][j] = __builtin_amdgcn_mfma_f32_16x16x32_bf16(al[i], bcur[j],
                                                              acc[i][j], 0, 0, 0);
        }
      if (tdo) ((uint4*)(tlo ? ringl : ringh))[tslot] = tv;
      if (kt + 1 < kt_lim) {
#pragma unroll
        for (int j = 0; j < 4; ++j) bcur[j] = bnx[j];
      }
    }

    // epilogue: y = acc  (D folded into K); C/D: col=lane&15, row=g*4+reg
#pragma unroll
    for (int i = 0; i < 4; ++i)
#pragma unroll
      for (int j = 0; j < 4; ++j) {
        int l = l0 + (wm << 6) + (i << 4) + (g << 2);
        int h = h0 + (((wn << 2) + j) << 4) + m;
        int off = (((b << 11) + l) << 9) + h;
#pragma unroll
        for (int r = 0; r < 4; ++r) y[off + (r << 9)] = acc[i][j][r];
      }
  }
}

extern "C" void kernel_launch(void* const* d_in, const int* in_sizes, int n_in,
                              void* d_out, int out_size, void* d_ws,
                              size_t ws_size, hipStream_t stream) {
  (void)in_sizes; (void)n_in; (void)out_size;
  const float* u = (const float*)d_in[0];
  const float* B_ssm = (const float*)d_in[1];
  const float* C_ssm = (const float*)d_in[2];
  const float* D_skip = (const float*)d_in[3];
  const float* log_dt = (const float*)d_in[4];
  float* y = (float*)d_out;

  const size_t UBF_BYTES = (size_t)16 * 64 * 2048 * 16;  // 32 MB
  const size_t RG_BYTES = (size_t)2176 * 16 * 2 + 256;
  int use_ubf = (ws_size >= UBF_BYTES + RG_BYTES) ? 1 : 0;
  char* wsb = (char*)d_ws;
  uint4* ubf = (uint4*)wsb;
  uint4* rg_hi = use_ubf ? (uint4*)(wsb + UBF_BYTES) : (uint4*)wsb;
  uint4* rg_lo = rg_hi + 2176;
  int* wsi = (int*)(rg_lo + 2176);

  prep_quant<<<use_ubf ? 2049 : 1, 256, 0, stream>>>(
      u, B_ssm, C_ssm, D_skip, log_dt, rg_hi, rg_lo, wsi, ubf);
  conv_kernel<<<512, 256, 0, stream>>>(u, rg_hi, rg_lo, ubf, wsi, y, use_ubf);
}

// Round 5
// 211.457 us; speedup vs baseline: 1.1666x; 1.0326x over previous
//
#include <hip/hip_runtime.h>
#include <math.h>

// ---------------------------------------------------------------------------
// S4 conv:  y[b,l,h] = sum_{t<=l} K[2047-(l-t)]*u[t,h] + D*u[l,h]
// prep_quant (block 0): expm(dt*A) via order-9 Taylor + scaling/squaring on
//   MATRIX CORES (bf16 hi/lo split 3-product MFMA, R6); B_bar fp64 solve;
//   log-depth doubling scans -> K; ring tables rg_hi/rg_lo + cutoff.
// prep_quant (blocks 1..2048): quantize u -> bf16 B-fragment layout (ubf).
// conv (512 blocks): 128x128 bf16 MFMA, 2-product (Khi,Klo).
//
// R6->R7 (counters: prep 83us, MfmaUtil 0.02 -> block-0 glue is latency):
//   - solve: P_i via 1 sqrt/lane + __shfl products (was 2 fp64 sqrts/iter
//     inside the 64-deep dependent loop)
//   - X-init Aval via LDS P-table (was 32 fp64 sqrts/thread)
//   - V-scan matvecs read fp32 M from b1 (maintained by squarings' oF32
//     path, free) -> no bf2f shifts, half the FMAs; 2-way partial sums
//   - W-scan/K-dot: independent partial accumulators (ILP)
//   - conv: XCD-aware bijective block swizzle (512%8==0): each XCD gets 2
//     batches -> ubf working set 4MB = L2 -> re-read traffic 272MB -> ~32MB
// ---------------------------------------------------------------------------

typedef short short8 __attribute__((ext_vector_type(8)));
typedef short short4v __attribute__((ext_vector_type(4)));
typedef float f32x4 __attribute__((ext_vector_type(4)));

#define SWMASK 28
__device__ __forceinline__ int swz(int r, int c) {
  return (r << 6) + (c ^ (r & SWMASK));
}
__device__ __forceinline__ float Aval(int i, int j) {
  if (i > j)  return -(float)(sqrt(2.0 * i + 1.0) * sqrt(2.0 * j + 1.0));
  if (i == j) return -(float)(i + 1);
  return 0.0f;
}
__device__ __forceinline__ unsigned rne_bf16(float x) {
  unsigned u = __float_as_uint(x);
  return (u + 0x7FFFu + ((u >> 16) & 1u)) >> 16;
}
__device__ __forceinline__ float invfact(int k) {
  switch (k) {
    case 0: return 1.0f;            case 1: return 1.0f;
    case 2: return 0.5f;            case 3: return (float)(1.0/6.0);
    case 4: return (float)(1.0/24.0);       case 5: return (float)(1.0/120.0);
    case 6: return (float)(1.0/720.0);      case 7: return (float)(1.0/5040.0);
    case 8: return (float)(1.0/40320.0);    default: return (float)(1.0/362880.0);
  }
}
// split-buffer addressing: ushort[64 rows][64 k], 16B slots XOR-swizzled.
__device__ __forceinline__ int slotU(int row, int kg) {
  return (row << 6) + ((kg ^ (row & 7)) << 3);
}
__device__ __forceinline__ float bf2f(unsigned short s) {
  return __uint_as_float(((unsigned)s) << 16);
}
__device__ __forceinline__ unsigned short bfh(float x) {
  return (unsigned short)rne_bf16(x);
}
__device__ __forceinline__ unsigned short bfl(float x, unsigned short h) {
  return (unsigned short)rne_bf16(x - __uint_as_float(((unsigned)h) << 16));
}

// C = L*R (+ cI*I + cX*Xg). rowL* = row-form splits of L, colR* = col-form
// splits of R. Optional outputs: col-form (oCol*), row-form (oRow*), fp32
// swizzled (oF32). A/B frag: lane=(g,m) holds 8 consecutive k of row/col m,
// k base = 32*kt + 8*g.  C/D: row = 4g+r, col = m (per 16x16 tile).
__device__ __forceinline__ void mmMFMA(
    const unsigned short* rowLh, const unsigned short* rowLl,
    const unsigned short* colRh, const unsigned short* colRl,
    unsigned short* oColH, unsigned short* oColL,
    unsigned short* oRowH, unsigned short* oRowL,
    float* oF32, const float* Xg, float cI, float cX, int tid) {
  const int lane = tid & 63, w = tid >> 6;
  const int g = lane >> 4, m = lane & 15;
  const bool doN = (oColH != nullptr) || (oF32 != nullptr);
  const bool doT = (oRowH != nullptr);
  f32x4 an[4], at[4];

  if (doN) {  // normal: acc_n[nt][r] = C[16w+4g+r][16nt+m]
    short8 ah[2], al[2];
#pragma unroll
    for (int kt = 0; kt < 2; ++kt) {
      ah[kt] = *(const short8*)&rowLh[slotU(16 * w + m, 4 * kt + g)];
      al[kt] = *(const short8*)&rowLl[slotU(16 * w + m, 4 * kt + g)];
    }
#pragma unroll
    for (int nt = 0; nt < 4; ++nt) {
      an[nt] = (f32x4){0.f, 0.f, 0.f, 0.f};
#pragma unroll
      for (int kt = 0; kt < 2; ++kt) {
        short8 bh = *(const short8*)&colRh[slotU(16 * nt + m, 4 * kt + g)];
        short8 bl = *(const short8*)&colRl[slotU(16 * nt + m, 4 * kt + g)];
        an[nt] = __builtin_amdgcn_mfma_f32_16x16x32_bf16(ah[kt], bh, an[nt], 0, 0, 0);
        an[nt] = __builtin_amdgcn_mfma_f32_16x16x32_bf16(ah[kt], bl, an[nt], 0, 0, 0);
        an[nt] = __builtin_amdgcn_mfma_f32_16x16x32_bf16(al[kt], bh, an[nt], 0, 0, 0);
      }
      if (Xg) {
#pragma unroll
        for (int r = 0; r < 4; ++r) {
          int rc = 16 * w + 4 * g + r, cc = 16 * nt + m;
          float gv = cX * Xg[(rc << 6) + (cc ^ (rc & 28))];
          if (rc == cc) gv += cI;
          an[nt][r] += gv;
        }
      }
    }
  }
  if (doT) {  // transposed: acc_t[nt][r] = C[16nt+m][16w+4g+r]
    short8 ah[2], al[2];
#pragma unroll
    for (int kt = 0; kt < 2; ++kt) {
      ah[kt] = *(const short8*)&colRh[slotU(16 * w + m, 4 * kt + g)];
      al[kt] = *(const short8*)&colRl[slotU(16 * w + m, 4 * kt + g)];
    }
#pragma unroll
    for (int nt = 0; nt < 4; ++nt) {
      at[nt] = (f32x4){0.f, 0.f, 0.f, 0.f};
#pragma unroll
      for (int kt = 0; kt < 2; ++kt) {
        short8 bh = *(const short8*)&rowLh[slotU(16 * nt + m, 4 * kt + g)];
        short8 bl = *(const short8*)&rowLl[slotU(16 * nt + m, 4 * kt + g)];
        at[nt] = __builtin_amdgcn_mfma_f32_16x16x32_bf16(ah[kt], bh, at[nt], 0, 0, 0);
        at[nt] = __builtin_amdgcn_mfma_f32_16x16x32_bf16(ah[kt], bl, at[nt], 0, 0, 0);
        at[nt] = __builtin_amdgcn_mfma_f32_16x16x32_bf16(al[kt], bh, at[nt], 0, 0, 0);
      }
      if (Xg) {
        int rc = 16 * nt + m;
        int cb = 16 * w + 4 * g;
        f32x4 xv = *(const f32x4*)&Xg[(rc << 6) + (cb ^ (rc & 28))];
#pragma unroll
        for (int r = 0; r < 4; ++r) {
          float gv = cX * xv[r];
          if (rc == cb + r) gv += cI;
          at[nt][r] += gv;
        }
      }
    }
  }
  __syncthreads();  // all split reads done -> safe to overwrite splits
  const int k0 = 16 * w + 4 * g;
  if (doN) {
#pragma unroll
    for (int nt = 0; nt < 4; ++nt) {
      if (oColH) {
        short4v h4, l4;
#pragma unroll
        for (int r = 0; r < 4; ++r) {
          unsigned short h = bfh(an[nt][r]);
          h4[r] = (short)h;
          l4[r] = (short)bfl(an[nt][r], h);
        }
        int s = slotU(16 * nt + m, k0 >> 3) + (k0 & 7);
        *(short4v*)&oColH[s] = h4;
        *(short4v*)&oColL[s] = l4;
      }
      if (oF32) {
#pragma unroll
        for (int r = 0; r < 4; ++r) {
          int rc = k0 + r;
          oF32[(rc << 6) + ((16 * nt + m) ^ (rc & 28))] = an[nt][r];
        }
      }
    }
  }
  if (doT) {
#pragma unroll
    for (int nt = 0; nt < 4; ++nt) {
      short4v h4, l4;
#pragma unroll
      for (int r = 0; r < 4; ++r) {
        unsigned short h = bfh(at[nt][r]);
        h4[r] = (short)h;
        l4[r] = (short)bfl(at[nt][r], h);
      }
      int s = slotU(16 * nt + m, k0 >> 3) + (k0 & 7);
      *(short4v*)&oRowH[s] = h4;
      *(short4v*)&oRowL[s] = l4;
    }
  }
  __syncthreads();
}

__global__ __launch_bounds__(256) void prep_quant(
    const float* __restrict__ u, const float* __restrict__ B_ssm,
    const float* __restrict__ C_ssm, const float* __restrict__ D_skip,
    const float* __restrict__ log_dt, uint4* __restrict__ rg_hi,
    uint4* __restrict__ rg_lo, int* __restrict__ wsi,
    uint4* __restrict__ ubf) {
  __shared__ __align__(16) float smem[16384];  // 64 KB
  const int tid = threadIdx.x;

  if (blockIdx.x != 0) {
    // ---------------- u-quant block: (b, tc, half) -> ubf ----------------
    int q = blockIdx.x - 1;                 // 0..2047
    int b = q >> 7, rem = q & 127;
    int tc = rem >> 1, hf = rem & 1;
    int t0 = (tc << 5) + (hf << 4);
    float* S = smem;                        // [16][520]
#pragma unroll
    for (int r = 0; r < 8; ++r) {
      int s = tid + (r << 8);               // 2048 float4-slots
      int row = s >> 7, c4 = (s & 127) << 2;
      float4 v = *(const float4*)(u + ((((b << 11) + t0 + row) << 9) + c4));
      *(float4*)&S[row * 520 + c4] = v;
    }
    __syncthreads();
#pragma unroll
    for (int r = 0; r < 4; ++r) {
      int gidx = tid + (r << 8);            // 0..1023
      int jnG = gidx >> 5;                  // 0..31
      int gl = (gidx >> 4) & 1;
      int hm = gidx & 15;
      int gg = (hf << 1) | gl;
      int h = (jnG << 4) + hm;
      int tb = gl << 3;
      unsigned pk[4];
#pragma unroll
      for (int q2 = 0; q2 < 4; ++q2) {
        unsigned lo = rne_bf16(S[(tb + 2 * q2) * 520 + h]);
        unsigned hi = rne_bf16(S[(tb + 2 * q2 + 1) * 520 + h]);
        pk[q2] = lo | (hi << 16);
      }
      ubf[(((b << 6) | tc) << 11) | (jnG << 6) | (gg << 4) | hm] =
          make_uint4(pk[0], pk[1], pk[2], pk[3]);
    }
    return;
  }

  // ---------------- prep block ----------------
  float* b0 = smem;
  float* b1 = smem + 4096;
  float* b2 = smem + 8192;
  float* b3 = smem + 12288;
  unsigned short* RH = (unsigned short*)b2;   // row-form hi
  unsigned short* RL = RH + 4096;             // row-form lo
  unsigned short* CH = (unsigned short*)b3;   // col-form hi
  unsigned short* CL = CH + 4096;             // col-form lo
  unsigned short* X2H = (unsigned short*)b1;  // X2 col-form hi
  unsigned short* X2L = X2H + 4096;
  double* Pd = (double*)b3;                   // P table (temp, pre-X-init)
  const int lane = tid & 63, wv = tid >> 6;
  const float dtf = expf(log_dt[0]);

  // ||A||_1 column sums: cs[j] = (j+1) + P_j * sum_{i>j} P_i ; also P table
  if (tid < 64) {
    double p = sqrt(2.0 * tid + 1.0);
    Pd[tid] = p;
    double s = p;
#pragma unroll
    for (int off = 1; off < 64; off <<= 1) {
      double t = __shfl_down(s, off, 64);
      if (tid + off < 64) s += t;
    }
    b2[tid] = (float)((tid + 1.0) + p * (s - p));
  }
  __syncthreads();
  float maxc = 0.f;
  for (int j = 0; j < 64; ++j) maxc = fmaxf(maxc, b2[j]);
  int iE;
  frexpf(dtf * maxc, &iE);
  int sExp = iE > 0 ? iE : 0;  // eta <= 1.0; order-9 Taylor err ~7e-7
  const float scale = ldexpf(dtf, -sExp);
  __syncthreads();

  // ---- X init: fp32 (b0, swizzled) + row-splits (b2) + col-splits (b3)
  // Aval via P table (Pd in b3 -- read BEFORE col-split writes, then sync).
  const int r0i = (tid & 15) << 2, c0i = (tid >> 4) << 2;
  double pr_[4], pc_[4];
#pragma unroll
  for (int i = 0; i < 4; ++i) pr_[i] = Pd[r0i + i];
#pragma unroll
  for (int j = 0; j < 4; ++j) pc_[j] = Pd[c0i + j];
  __syncthreads();  // P reads done before CH/CL (b3) writes below
  float xv[4][4];
  unsigned short xh[4][4], xl[4][4];
#pragma unroll
  for (int i = 0; i < 4; ++i)
#pragma unroll
    for (int j = 0; j < 4; ++j) {
      int ri = r0i + i, cj = c0i + j;
      float a;
      if (ri > cj)       a = -(float)(pr_[i] * pc_[j]);
      else if (ri == cj) a = -(float)(ri + 1);
      else               a = 0.0f;
      float x = scale * a;
      xv[i][j] = x;
      xh[i][j] = bfh(x);
      xl[i][j] = bfl(x, xh[i][j]);
      b0[swz(ri, cj)] = x;
    }
#pragma unroll
  for (int i = 0; i < 4; ++i) {  // row-form [r0i+i][c0i..c0i+3]
    short4v h4, l4;
#pragma unroll
    for (int j = 0; j < 4; ++j) { h4[j] = (short)xh[i][j]; l4[j] = (short)xl[i][j]; }
    int s = slotU(r0i + i, c0i >> 3) + (c0i & 7);
    *(short4v*)&RH[s] = h4;
    *(short4v*)&RL[s] = l4;
  }
#pragma unroll
  for (int j = 0; j < 4; ++j) {  // col-form [c0i+j][r0i..r0i+3]
    short4v h4, l4;
#pragma unroll
    for (int i = 0; i < 4; ++i) { h4[i] = (short)xh[i][j]; l4[i] = (short)xl[i][j]; }
    int s = slotU(c0i + j, r0i >> 3) + (r0i & 7);
    *(short4v*)&CH[s] = h4;
    *(short4v*)&CL[s] = l4;
  }
  __syncthreads();

  // X2 = X*X -> col-form only (b1)
  mmMFMA(RH, RL, CH, CL, X2H, X2L, nullptr, nullptr, nullptr, nullptr,
         0.f, 0.f, tid);

  // G = c8*I + c9*X -> row-form (b2); X-row dead after X2's reads.
#pragma unroll
  for (int i = 0; i < 4; ++i) {
    short4v h4, l4;
#pragma unroll
    for (int j = 0; j < 4; ++j) {
      float gv = invfact(9) * xv[i][j];
      if (r0i + i == c0i + j) gv += invfact(8);
      unsigned short h = bfh(gv);
      h4[j] = (short)h;
      l4[j] = (short)bfl(gv, h);
    }
    int s = slotU(r0i + i, c0i >> 3) + (c0i & 7);
    *(short4v*)&RH[s] = h4;
    *(short4v*)&RL[s] = l4;
  }
  __syncthreads();

  // Horner m=3..1: P = P*X2 + (c2m*I + c2m+1*X) -> row-form only
  for (int mq = 3; mq >= 1; --mq)
    mmMFMA(RH, RL, X2H, X2L, nullptr, nullptr, RH, RL, nullptr, b0,
           invfact(2 * mq), invfact(2 * mq + 1), tid);
  // last Horner (m=0), E-form: E = P*X2 + 0*I + 1*X  (= e^X - I)
  // -> row (b2), col (b3), fp32 E (b1; overwrites X2col after reads)
  mmMFMA(RH, RL, X2H, X2L, CH, CL, RH, RL, b1, b0, 0.f, 1.f, tid);

  // exp-squarings in E-form: E' = E*E + 2*E  (Xg = old E fp32 in b1)
  for (int q = 0; q < sExp; ++q)
    mmMFMA(RH, RL, CH, CL, CH, CL, RH, RL, b1, b1, 0.f, 2.f, tid);

  // ---- diag fixup (M_0 = I + E in the splits) + load Bl; X fp32 dead.
  float* Bl = b0 + 64;
  if (tid < 64) {
    Bl[tid] = B_ssm[tid];
    int d = tid;
    float x = b1[(d << 6) + (d ^ (d & 28))] + 1.0f;
    unsigned short h = bfh(x), l = bfl(x, h);
    int s = slotU(d, d >> 3) + (d & 7);
    RH[s] = h; RL[s] = l; CH[s] = h; CL[s] = l;
  }
  __syncthreads();

  // B_bar: solve A x = E*B  (E = A_bar - I fp32 in b1; no cancellation)
  // P products via 1 sqrt/lane + shfl (no per-iter sqrts).
  if (tid < 64) {
    int i = tid;
    double pi = sqrt(2.0 * i + 1.0);
    double accd = 0.0;
#pragma unroll
    for (int k4 = 0; k4 < 16; ++k4) {
      int jM = (k4 << 2) ^ (i & 28);
      float4 mv = *(const float4*)&b1[(i << 6) + jM];
      float4 bv = *(const float4*)&Bl[k4 << 2];
      accd += (double)mv.x * bv.x + (double)mv.y * bv.y +
              (double)mv.z * bv.z + (double)mv.w * bv.w;
    }
    double xvv = 0.0;
    for (int j = 0; j < 64; ++j) {
      if (i == j) xvv = accd / (-(double)(j + 1));
      double xj = __shfl(xvv, j, 64);
      double pj = __shfl(pi, j, 64);
      if (i > j) accd += pi * pj * xj;  // accd -= Aval(i,j)*xj, Aval=-pi*pj
    }
    b0[i] = (float)xvv;  // Vt[0] = B_bar  (Vt: stride 64, XOR-swizzled)
    // M_0 fp32 diag (I + E) for V-scan matvecs
    b1[(i << 6) + (i ^ (i & 28))] += 1.0f;
  }
  __syncthreads();

  // V doubling: v_{t+2^k} = M_k v_t (fp32 M from b1!), then square.
  for (int k = 0; k < 6; ++k) {
    int cnt = 1 << k;
    for (int t = wv; t < cnt; t += 4) {
      float a0 = 0.f, a1 = 0.f;
#pragma unroll
      for (int k4 = 0; k4 < 16; ++k4) {
        int jM = (k4 << 2) ^ (lane & 28);
        f32x4 mv = *(const f32x4*)&b1[(lane << 6) + jM];
        f32x4 vvv = *(const f32x4*)&b0[(t << 6) + ((k4 << 2) ^ (t & 28))];
        a0 = fmaf(mv[0], vvv[0], fmaf(mv[1], vvv[1], a0));
        a1 = fmaf(mv[2], vvv[2], fmaf(mv[3], vvv[3], a1));
      }
      int td = t + cnt;
      b0[(td << 6) + (lane ^ (td & 28))] = a0 + a1;
    }
    // square M_k -> M_{k+1} (splits + fp32 b1); first barrier covers matvec
    mmMFMA(RH, RL, CH, CL, CH, CL, RH, RL, b1, nullptr, 0.f, 0.f, tid);
  }

  // W init: w_0 = C  (Wt: b1, plain stride 64; fp32 M_6 dead)
  if (tid < 64) b1[tid] = C_ssm[tid];
  __syncthreads();
  // W doubling (column-form splits, untransposed): w'[i] = sum_j w[j] M[j][i]
  for (int k = 0; k < 5; ++k) {
    int cnt = 1 << k;
    for (int t = wv; t < cnt; t += 4) {
      float ah = 0.f, al = 0.f;
#pragma unroll
      for (int kg = 0; kg < 8; ++kg) {
        short8 ch8 = *(const short8*)&CH[slotU(lane, kg)];
        short8 cl8 = *(const short8*)&CL[slotU(lane, kg)];
        f32x4 w0 = *(const f32x4*)&b1[(t << 6) + (kg << 3)];
        f32x4 w1 = *(const f32x4*)&b1[(t << 6) + (kg << 3) + 4];
#pragma unroll
        for (int j = 0; j < 4; ++j) {
          ah = fmaf(bf2f((unsigned short)ch8[j]), w0[j], ah);
          al = fmaf(bf2f((unsigned short)cl8[j]), w0[j], al);
        }
#pragma unroll
        for (int j = 0; j < 4; ++j) {
          ah = fmaf(bf2f((unsigned short)ch8[4 + j]), w1[j], ah);
          al = fmaf(bf2f((unsigned short)cl8[4 + j]), w1[j], al);
        }
      }
      b1[((t + cnt) << 6) + lane] = ah + al;
    }
    if (k < 3) {
      mmMFMA(RH, RL, CH, CL, CH, CL, RH, RL, nullptr, nullptr, 0.f, 0.f, tid);
    } else if (k == 3) {
      // M_10 only consumed col-form by level-4 matvec
      mmMFMA(RH, RL, CH, CL, CH, CL, nullptr, nullptr, nullptr, nullptr,
             0.f, 0.f, tid);
    } else {
      __syncthreads();  // after last matvec, before K overwrites b3
    }
  }

  // K[64t'+t] = w_t' . v_t  -> K in b3 (col-splits dead)
  float* K = b3;
  for (int x = tid; x < 2048; x += 256) {
    int tp = x >> 6, t = x & 63;
    float d0 = 0.f, d1 = 0.f;
#pragma unroll
    for (int i4 = 0; i4 < 64; i4 += 4) {
      f32x4 wv4 = *(const f32x4*)&b1[(tp << 6) + i4];
      f32x4 vv4 = *(const f32x4*)&b0[(t << 6) + (i4 ^ (t & 28))];
      d0 = fmaf(wv4[0], vv4[0], fmaf(wv4[1], vv4[1], d0));
      d1 = fmaf(wv4[2], vv4[2], fmaf(wv4[3], vv4[3], d1));
    }
    K[x] = d0 + d1;
  }
  __syncthreads();

  // split (with D folded at x=2047) -> kh/kl (b2); suffix-energy partials
  unsigned short* kh = (unsigned short*)b2;
  unsigned short* kl = kh + 2192;
  float* ss = (float*)(kh + 4400);
  const float D = D_skip[0];
  for (int x = tid; x < 2192; x += 256) {
    float v = 0.f;
    if (x < 2048) { v = K[x]; if (x == 2047) v += D; }
    unsigned h = rne_bf16(v);
    float hf2 = __uint_as_float(h << 16);
    unsigned l = rne_bf16(v - hf2);
    kh[x] = (unsigned short)h;
    kl[x] = (unsigned short)l;
  }
  {
    float ssum = 0.f;
#pragma unroll
    for (int q = 0; q < 8; ++q) {
      int x = (tid << 3) + q;
      float v = K[x];
      if (x == 2047) v += D;
      ssum += v * v;
    }
    ss[tid] = ssum;
  }
  __syncthreads();

  // ring tables: rg[e] = krev16[e..e+7]
  for (int e = tid; e < 2176; e += 256) {
    unsigned ph[4], pl[4];
#pragma unroll
    for (int q2 = 0; q2 < 4; ++q2) {
      ph[q2] = (unsigned)kh[e + 2 * q2] | ((unsigned)kh[e + 2 * q2 + 1] << 16);
      pl[q2] = (unsigned)kl[e + 2 * q2] | ((unsigned)kl[e + 2 * q2 + 1] << 16);
    }
    rg_hi[e] = make_uint4(ph[0], ph[1], ph[2], ph[3]);
    rg_lo[e] = make_uint4(pl[0], pl[1], pl[2], pl[3]);
  }
  if (tid == 0) {
    float accq = 0.f;
    int xt = 0;
    for (int jc = 255; jc >= 0; --jc) {
      float na = accq + ss[jc];
      if (na > 4e-8f) { xt = (jc + 1) << 3; break; }
      accq = na;
    }
    wsi[0] = 2048 - xt;
  }
}

// ---------------------------------------------------------------------------
// conv kernel
// ---------------------------------------------------------------------------
__device__ __forceinline__ void load_bfrag(short8* bf, const uint4* ubf,
                                           const float* u, int use_ubf, int b,
                                           int kt, int h0, int wn, int lane) {
  if (use_ubf) {
    const short8* base = (const short8*)(ubf + ((((b << 6) | kt) << 11) |
                                               (((h0 >> 4) + (wn << 2)) << 6) |
                                               lane));
#pragma unroll
    for (int j = 0; j < 4; ++j) bf[j] = base[j << 6];
  } else {
    int gg = lane >> 4, hm = lane & 15;
#pragma unroll
    for (int j = 0; j < 4; ++j) {
      const float* src = u + ((((b << 11) + (kt << 5) + (gg << 3)) << 9) + h0 +
                              (((wn << 2) + j) << 4) + hm);
      unsigned pk[4];
#pragma unroll
      for (int q = 0; q < 4; ++q) {
        unsigned lo = rne_bf16(src[q << 10]);
        unsigned hi = rne_bf16(src[(q << 10) + 512]);
        pk[q] = lo | (hi << 16);
      }
      uint4 vv = make_uint4(pk[0], pk[1], pk[2], pk[3]);
      bf[j] = __builtin_bit_cast(short8, vv);
    }
  }
}

__global__ __launch_bounds__(256) void conv_kernel(
    const float* __restrict__ u, const uint4* __restrict__ rg_hi,
    const uint4* __restrict__ rg_lo, const uint4* __restrict__ ubf,
    const int* __restrict__ wsi, float* __restrict__ y, int use_ubf) {
  __shared__ __align__(16) unsigned ringh[1024], ringl[1024];  // 256x16B each
  const int tid = threadIdx.x;
  // XCD-aware bijective swizzle (8 XCDs, 512 blocks): XCD x works on logical
  // blocks [64x, 64x+64) = exactly 2 batches -> ubf working set 4MB = L2.
  const int bid0 = blockIdx.x;
  const int bid = ((bid0 & 7) << 6) | (bid0 >> 3);
  const int b = bid >> 5;
  const int bn = bid & 3;
  const int pr = (bid >> 2) & 7;
  const int h0 = bn << 7;
  const int lane = tid & 63, w = tid >> 6;
  const int wm = w & 1, wn = w >> 1;
  const int g = lane >> 4, m = lane & 15;
  const int D_lo = wsi[0];

  for (int tile = 0; tile < 2; ++tile) {
    const int bm = tile ? pr : 15 - pr;
    const int l0 = bm << 7;
    const int e0 = 1920 - l0;
    const int ktiles = 4 * bm + 4;
    int kt_lim = ((l0 + 127 - D_lo) >> 5) + 1;
    if (kt_lim < 0) kt_lim = 0;
    if (kt_lim > ktiles) kt_lim = ktiles;

    __syncthreads();  // previous tile's ring reads complete
    for (int tsk = tid; tsk < 432; tsk += 256) {
      int isLo = tsk >= 216;
      int e = e0 + (isLo ? tsk - 216 : tsk);
      if (e <= 2175) {
        uint4 v = isLo ? rg_lo[e] : rg_hi[e];
        ((uint4*)(isLo ? ringl : ringh))[e & 255] = v;
      }
    }

    f32x4 acc[4][4];
#pragma unroll
    for (int i = 0; i < 4; ++i)
#pragma unroll
      for (int j = 0; j < 4; ++j) acc[i][j] = (f32x4){0.f, 0.f, 0.f, 0.f};

    short8 bcur[4];
    if (kt_lim > 0) load_bfrag(bcur, ubf, u, use_ubf, b, 0, h0, wn, lane);

    for (int kt = 0; kt < kt_lim; ++kt) {
      __syncthreads();  // ring writes visible
      uint4 tv;
      bool tdo = false;
      int tslot = 0;
      const bool tlo = (tid >= 32);
      if (tid < 64) {
        int te = e0 + 216 + (kt << 5) + (tid & 31);
        if (te <= 2175) {
          tv = tlo ? rg_lo[te] : rg_hi[te];
          tdo = true;
          tslot = te & 255;
        }
      }
      const int ebase = 2047 - l0 + (kt << 5) - (wm << 6) - m + (g << 3);
      short8 ah[4], al[4];
#pragma unroll
      for (int i = 0; i < 4; ++i) {
        int slot = (ebase - (i << 4)) & 255;
        ah[i] = ((const short8*)ringh)[slot];
        al[i] = ((const short8*)ringl)[slot];
      }
      short8 bnx[4];
      if (kt + 1 < kt_lim)
        load_bfrag(bnx, ubf, u, use_ubf, b, kt + 1, h0, wn, lane);
#pragma unroll
      for (int i = 0; i < 4; ++i)
#pragma unroll
        for (int j = 0; j < 4; ++j) {
          acc[i][j] = __builtin_amdgcn_mfma_f32_16x16x32_bf16(ah[i], bcur[j],
                                                              acc[i][j], 0, 0, 0);
          acc[i][j] = __builtin_amdgcn_mfma_f32_16x16x32_bf16(al[i], bcur[j],
                                                              acc[i][j], 0, 0, 0);
        }
      if (tdo) ((uint4*)(tlo ? ringl : ringh))[tslot] = tv;
      if (kt + 1 < kt_lim) {
#pragma unroll
        for (int j = 0; j < 4; ++j) bcur[j] = bnx[j];
      }
    }

    // epilogue: y = acc  (D folded into K); C/D: col=lane&15, row=g*4+reg
#pragma unroll
    for (int i = 0; i < 4; ++i)
#pragma unroll
      for (int j = 0; j < 4; ++j) {
        int l = l0 + (wm << 6) + (i << 4) + (g << 2);
        int h = h0 + (((wn << 2) + j) << 4) + m;
        int off = (((b << 11) + l) << 9) + h;
#pragma unroll
        for (int r = 0; r < 4; ++r) y[off + (r << 9)] = acc[i][j][r];
      }
  }
}

extern "C" void kernel_launch(void* const* d_in, const int* in_sizes, int n_in,
                              void* d_out, int out_size, void* d_ws,
                              size_t ws_size, hipStream_t stream) {
  (void)in_sizes; (void)n_in; (void)out_size;
  const float* u = (const float*)d_in[0];
  const float* B_ssm = (const float*)d_in[1];
  const float* C_ssm = (const float*)d_in[2];
  const float* D_skip = (const float*)d_in[3];
  const float* log_dt = (const float*)d_in[4];
  float* y = (float*)d_out;

  const size_t UBF_BYTES = (size_t)16 * 64 * 2048 * 16;  // 32 MB
  const size_t RG_BYTES = (size_t)2176 * 16 * 2 + 256;
  int use_ubf = (ws_size >= UBF_BYTES + RG_BYTES) ? 1 : 0;
  char* wsb = (char*)d_ws;
  uint4* ubf = (uint4*)wsb;
  uint4* rg_hi = use_ubf ? (uint4*)(wsb + UBF_BYTES) : (uint4*)wsb;
  uint4* rg_lo = rg_hi + 2176;
  int* wsi = (int*)(rg_lo + 2176);

  prep_quant<<<use_ubf ? 2049 : 1, 256, 0, stream>>>(
      u, B_ssm, C_ssm, D_skip, log_dt, rg_hi, rg_lo, wsi, ubf);
  conv_kernel<<<512, 256, 0, stream>>>(u, rg_hi, rg_lo, ubf, wsi, y, use_ubf);
}

// Round 6
// 202.509 us; speedup vs baseline: 1.2181x; 1.0442x over previous
//
#include <hip/hip_runtime.h>
#include <math.h>

// ---------------------------------------------------------------------------
// S4 conv:  y[b,l,h] = sum_{t<=l} K[2047-(l-t)]*u[t,h] + D*u[l,h]
// prep_quant (block 0): expm(dt*A) via order-9 Taylor + scaling/squaring on
//   MATRIX CORES (bf16 hi/lo split 3-product MFMA); B_bar fp64 solve;
//   log-depth doubling scans -> K; ring tables rg_hi/rg_lo + cutoff.
// prep_quant (blocks 1..2048): quantize u -> bf16 B-fragment layout (ubf).
// conv (512 blocks): 128x128 bf16 MFMA, 2-product (Khi,Klo), XCD swizzle.
//
// R7->R8: prep block widened 256 -> 1024 threads (16 waves = 4/SIMD).
//   Block-0 was 1 wave/SIMD: LDS latency, conversion VALU chains and barrier
//   drains fully exposed (tail ~56us vs ~25us issue model). mmMFMA retiled:
//   wave (wr,wc) computes ONE 16x16 tile per orientation (12 MFMA + 16
//   ds_read_b128 + ~80 VALU per wave vs 48/40/~640) -> 4x issue parallelism,
//   4-deep latency hiding. Scans/K/ring re-strided to 16 waves. Numerics
//   bitwise identical (same per-element MFMA sequence, fp32/fp64 paths).
// ---------------------------------------------------------------------------

typedef short short8 __attribute__((ext_vector_type(8)));
typedef short short4v __attribute__((ext_vector_type(4)));
typedef float f32x4 __attribute__((ext_vector_type(4)));

#define SWMASK 28
__device__ __forceinline__ int swz(int r, int c) {
  return (r << 6) + (c ^ (r & SWMASK));
}
__device__ __forceinline__ unsigned rne_bf16(float x) {
  unsigned u = __float_as_uint(x);
  return (u + 0x7FFFu + ((u >> 16) & 1u)) >> 16;
}
__device__ __forceinline__ float invfact(int k) {
  switch (k) {
    case 0: return 1.0f;            case 1: return 1.0f;
    case 2: return 0.5f;            case 3: return (float)(1.0/6.0);
    case 4: return (float)(1.0/24.0);       case 5: return (float)(1.0/120.0);
    case 6: return (float)(1.0/720.0);      case 7: return (float)(1.0/5040.0);
    case 8: return (float)(1.0/40320.0);    default: return (float)(1.0/362880.0);
  }
}
// split-buffer addressing: ushort[64 rows][64 k], 16B slots XOR-swizzled.
__device__ __forceinline__ int slotU(int row, int kg) {
  return (row << 6) + ((kg ^ (row & 7)) << 3);
}
__device__ __forceinline__ float bf2f(unsigned short s) {
  return __uint_as_float(((unsigned)s) << 16);
}
__device__ __forceinline__ unsigned short bfh(float x) {
  return (unsigned short)rne_bf16(x);
}
__device__ __forceinline__ unsigned short bfl(float x, unsigned short h) {
  return (unsigned short)rne_bf16(x - __uint_as_float(((unsigned)h) << 16));
}

// C = L*R (+ cI*I + cX*Xg), 16-wave version: wave w=(wr=w&3, wc=w>>2)
// computes C tile (wr,wc) [doN] and the mirrored C^T tile [doT].
// A/B frag: lane=(g,m) holds 8 consecutive k of row/col m, k base 32kt+8g.
// C/D: row=4g+r, col=m (per 16x16 tile). Two barriers: after compute
// (before overwriting splits), after writes.
__device__ __forceinline__ void mmMFMA(
    const unsigned short* rowLh, const unsigned short* rowLl,
    const unsigned short* colRh, const unsigned short* colRl,
    unsigned short* oColH, unsigned short* oColL,
    unsigned short* oRowH, unsigned short* oRowL,
    float* oF32, const float* Xg, float cI, float cX, int tid) {
  const int lane = tid & 63, w = tid >> 6;   // w in 0..15
  const int wr = w & 3, wc = w >> 2;
  const int g = lane >> 4, m = lane & 15;
  const bool doN = (oColH != nullptr) || (oF32 != nullptr);
  const bool doT = (oRowH != nullptr);
  f32x4 an = (f32x4){0.f, 0.f, 0.f, 0.f};
  f32x4 at = (f32x4){0.f, 0.f, 0.f, 0.f};

  if (doN) {  // an[r] = C[16wr+4g+r][16wc+m]
#pragma unroll
    for (int kt = 0; kt < 2; ++kt) {
      short8 ah = *(const short8*)&rowLh[slotU(16 * wr + m, 4 * kt + g)];
      short8 al = *(const short8*)&rowLl[slotU(16 * wr + m, 4 * kt + g)];
      short8 bh = *(const short8*)&colRh[slotU(16 * wc + m, 4 * kt + g)];
      short8 bl = *(const short8*)&colRl[slotU(16 * wc + m, 4 * kt + g)];
      an = __builtin_amdgcn_mfma_f32_16x16x32_bf16(ah, bh, an, 0, 0, 0);
      an = __builtin_amdgcn_mfma_f32_16x16x32_bf16(ah, bl, an, 0, 0, 0);
      an = __builtin_amdgcn_mfma_f32_16x16x32_bf16(al, bh, an, 0, 0, 0);
    }
    if (Xg) {
#pragma unroll
      for (int r = 0; r < 4; ++r) {
        int rc = 16 * wr + 4 * g + r, cc = 16 * wc + m;
        float gv = cX * Xg[(rc << 6) + (cc ^ (rc & 28))];
        if (rc == cc) gv += cI;
        an[r] += gv;
      }
    }
  }
  if (doT) {  // at[r] = C[16wc+m][16wr+4g+r]  (C^T via swapped operands)
#pragma unroll
    for (int kt = 0; kt < 2; ++kt) {
      short8 ah = *(const short8*)&colRh[slotU(16 * wr + m, 4 * kt + g)];
      short8 al = *(const short8*)&colRl[slotU(16 * wr + m, 4 * kt + g)];
      short8 bh = *(const short8*)&rowLh[slotU(16 * wc + m, 4 * kt + g)];
      short8 bl = *(const short8*)&rowLl[slotU(16 * wc + m, 4 * kt + g)];
      at = __builtin_amdgcn_mfma_f32_16x16x32_bf16(ah, bh, at, 0, 0, 0);
      at = __builtin_amdgcn_mfma_f32_16x16x32_bf16(ah, bl, at, 0, 0, 0);
      at = __builtin_amdgcn_mfma_f32_16x16x32_bf16(al, bh, at, 0, 0, 0);
    }
    if (Xg) {
      int rc = 16 * wc + m;
      int cb = 16 * wr + 4 * g;
      f32x4 xv = *(const f32x4*)&Xg[(rc << 6) + (cb ^ (rc & 28))];
#pragma unroll
      for (int r = 0; r < 4; ++r) {
        float gv = cX * xv[r];
        if (rc == cb + r) gv += cI;
        at[r] += gv;
      }
    }
  }
  __syncthreads();  // all split reads done -> safe to overwrite splits
  const int k0 = 16 * wr + 4 * g;
  if (doN) {
    if (oColH) {
      short4v h4, l4;
#pragma unroll
      for (int r = 0; r < 4; ++r) {
        unsigned short h = bfh(an[r]);
        h4[r] = (short)h;
        l4[r] = (short)bfl(an[r], h);
      }
      int s = slotU(16 * wc + m, k0 >> 3) + (k0 & 7);
      *(short4v*)&oColH[s] = h4;
      *(short4v*)&oColL[s] = l4;
    }
    if (oF32) {
#pragma unroll
      for (int r = 0; r < 4; ++r) {
        int rc = k0 + r;
        oF32[(rc << 6) + ((16 * wc + m) ^ (rc & 28))] = an[r];
      }
    }
  }
  if (doT) {
    short4v h4, l4;
#pragma unroll
    for (int r = 0; r < 4; ++r) {
      unsigned short h = bfh(at[r]);
      h4[r] = (short)h;
      l4[r] = (short)bfl(at[r], h);
    }
    int s = slotU(16 * wc + m, k0 >> 3) + (k0 & 7);
    *(short4v*)&oRowH[s] = h4;
    *(short4v*)&oRowL[s] = l4;
  }
  __syncthreads();
}

__global__ __launch_bounds__(1024, 1) void prep_quant(
    const float* __restrict__ u, const float* __restrict__ B_ssm,
    const float* __restrict__ C_ssm, const float* __restrict__ D_skip,
    const float* __restrict__ log_dt, uint4* __restrict__ rg_hi,
    uint4* __restrict__ rg_lo, int* __restrict__ wsi,
    uint4* __restrict__ ubf) {
  __shared__ __align__(16) float smem[16384];  // 64 KB
  const int tid = threadIdx.x;

  if (blockIdx.x != 0) {
    // ---------------- u-quant block: (b, tc, half) -> ubf ----------------
    int q = blockIdx.x - 1;                 // 0..2047
    int b = q >> 7, rem = q & 127;
    int tc = rem >> 1, hf = rem & 1;
    int t0 = (tc << 5) + (hf << 4);
    float* S = smem;                        // [16][520]
#pragma unroll
    for (int r = 0; r < 2; ++r) {
      int s = tid + (r << 10);              // 2048 float4-slots
      int row = s >> 7, c4 = (s & 127) << 2;
      float4 v = *(const float4*)(u + ((((b << 11) + t0 + row) << 9) + c4));
      *(float4*)&S[row * 520 + c4] = v;
    }
    __syncthreads();
    {
      int gidx = tid;                       // 0..1023
      int jnG = gidx >> 5;                  // 0..31
      int gl = (gidx >> 4) & 1;
      int hm = gidx & 15;
      int gg = (hf << 1) | gl;
      int h = (jnG << 4) + hm;
      int tb = gl << 3;
      unsigned pk[4];
#pragma unroll
      for (int q2 = 0; q2 < 4; ++q2) {
        unsigned lo = rne_bf16(S[(tb + 2 * q2) * 520 + h]);
        unsigned hi = rne_bf16(S[(tb + 2 * q2 + 1) * 520 + h]);
        pk[q2] = lo | (hi << 16);
      }
      ubf[(((b << 6) | tc) << 11) | (jnG << 6) | (gg << 4) | hm] =
          make_uint4(pk[0], pk[1], pk[2], pk[3]);
    }
    return;
  }

  // ---------------- prep block (1024 threads, 16 waves) ----------------
  float* b0 = smem;
  float* b1 = smem + 4096;
  float* b2 = smem + 8192;
  float* b3 = smem + 12288;
  unsigned short* RH = (unsigned short*)b2;   // row-form hi
  unsigned short* RL = RH + 4096;             // row-form lo
  unsigned short* CH = (unsigned short*)b3;   // col-form hi
  unsigned short* CL = CH + 4096;             // col-form lo
  unsigned short* X2H = (unsigned short*)b1;  // X2 col-form hi
  unsigned short* X2L = X2H + 4096;
  double* Pd = (double*)b3;                   // P table (temp, pre-X-init)
  const int lane = tid & 63, wv = tid >> 6;   // wv 0..15
  const float dtf = expf(log_dt[0]);

  // ||A||_1 column sums: cs[j] = (j+1) + P_j * sum_{i>j} P_i ; also P table
  if (tid < 64) {
    double p = sqrt(2.0 * tid + 1.0);
    Pd[tid] = p;
    double s = p;
#pragma unroll
    for (int off = 1; off < 64; off <<= 1) {
      double t = __shfl_down(s, off, 64);
      if (tid + off < 64) s += t;
    }
    b2[tid] = (float)((tid + 1.0) + p * (s - p));
  }
  __syncthreads();
  float maxc = 0.f;
  for (int j = 0; j < 64; ++j) maxc = fmaxf(maxc, b2[j]);
  int iE;
  frexpf(dtf * maxc, &iE);
  int sExp = iE > 0 ? iE : 0;  // eta <= 1.0; order-9 Taylor err ~7e-7
  const float scale = ldexpf(dtf, -sExp);
  __syncthreads();

  // ---- X init (threads 0..255, 4x4 each): fp32 (b0) + row/col splits
  const int r0i = (tid & 15) << 2, c0i = ((tid >> 4) & 15) << 2;
  double pr_[4], pc_[4];
  float xv[4][4];
  if (tid < 256) {
#pragma unroll
    for (int i = 0; i < 4; ++i) pr_[i] = Pd[r0i + i];
#pragma unroll
    for (int j = 0; j < 4; ++j) pc_[j] = Pd[c0i + j];
  }
  __syncthreads();  // P reads done before CH/CL (b3) writes below
  if (tid < 256) {
    unsigned short xh[4][4], xl[4][4];
#pragma unroll
    for (int i = 0; i < 4; ++i)
#pragma unroll
      for (int j = 0; j < 4; ++j) {
        int ri = r0i + i, cj = c0i + j;
        float a;
        if (ri > cj)       a = -(float)(pr_[i] * pc_[j]);
        else if (ri == cj) a = -(float)(ri + 1);
        else               a = 0.0f;
        float x = scale * a;
        xv[i][j] = x;
        xh[i][j] = bfh(x);
        xl[i][j] = bfl(x, xh[i][j]);
        b0[swz(ri, cj)] = x;
      }
#pragma unroll
    for (int i = 0; i < 4; ++i) {  // row-form [r0i+i][c0i..c0i+3]
      short4v h4, l4;
#pragma unroll
      for (int j = 0; j < 4; ++j) { h4[j] = (short)xh[i][j]; l4[j] = (short)xl[i][j]; }
      int s = slotU(r0i + i, c0i >> 3) + (c0i & 7);
      *(short4v*)&RH[s] = h4;
      *(short4v*)&RL[s] = l4;
    }
#pragma unroll
    for (int j = 0; j < 4; ++j) {  // col-form [c0i+j][r0i..r0i+3]
      short4v h4, l4;
#pragma unroll
      for (int i = 0; i < 4; ++i) { h4[i] = (short)xh[i][j]; l4[i] = (short)xl[i][j]; }
      int s = slotU(c0i + j, r0i >> 3) + (r0i & 7);
      *(short4v*)&CH[s] = h4;
      *(short4v*)&CL[s] = l4;
    }
  }
  __syncthreads();

  // X2 = X*X -> col-form only (b1)
  mmMFMA(RH, RL, CH, CL, X2H, X2L, nullptr, nullptr, nullptr, nullptr,
         0.f, 0.f, tid);

  // G = c8*I + c9*X -> row-form (b2); X-row dead after X2's reads.
  if (tid < 256) {
#pragma unroll
    for (int i = 0; i < 4; ++i) {
      short4v h4, l4;
#pragma unroll
      for (int j = 0; j < 4; ++j) {
        float gv = invfact(9) * xv[i][j];
        if (r0i + i == c0i + j) gv += invfact(8);
        unsigned short h = bfh(gv);
        h4[j] = (short)h;
        l4[j] = (short)bfl(gv, h);
      }
      int s = slotU(r0i + i, c0i >> 3) + (c0i & 7);
      *(short4v*)&RH[s] = h4;
      *(short4v*)&RL[s] = l4;
    }
  }
  __syncthreads();

  // Horner m=3..1: P = P*X2 + (c2m*I + c2m+1*X) -> row-form only
  for (int mq = 3; mq >= 1; --mq)
    mmMFMA(RH, RL, X2H, X2L, nullptr, nullptr, RH, RL, nullptr, b0,
           invfact(2 * mq), invfact(2 * mq + 1), tid);
  // last Horner (m=0), E-form: E = P*X2 + 0*I + 1*X  (= e^X - I)
  // -> row (b2), col (b3), fp32 E (b1; overwrites X2col after reads)
  mmMFMA(RH, RL, X2H, X2L, CH, CL, RH, RL, b1, b0, 0.f, 1.f, tid);

  // exp-squarings in E-form: E' = E*E + 2*E  (Xg = old E fp32 in b1)
  for (int q = 0; q < sExp; ++q)
    mmMFMA(RH, RL, CH, CL, CH, CL, RH, RL, b1, b1, 0.f, 2.f, tid);

  // ---- diag fixup (M_0 = I + E in the splits) + load Bl; X fp32 dead.
  float* Bl = b0 + 64;
  if (tid < 64) {
    Bl[tid] = B_ssm[tid];
    int d = tid;
    float x = b1[(d << 6) + (d ^ (d & 28))] + 1.0f;
    unsigned short h = bfh(x), l = bfl(x, h);
    int s = slotU(d, d >> 3) + (d & 7);
    RH[s] = h; RL[s] = l; CH[s] = h; CL[s] = l;
  }
  __syncthreads();

  // B_bar: solve A x = E*B  (E = A_bar - I fp32 in b1; no cancellation)
  if (tid < 64) {
    int i = tid;
    double pi = sqrt(2.0 * i + 1.0);
    double accd = 0.0;
#pragma unroll
    for (int k4 = 0; k4 < 16; ++k4) {
      int jM = (k4 << 2) ^ (i & 28);
      float4 mv = *(const float4*)&b1[(i << 6) + jM];
      float4 bv = *(const float4*)&Bl[k4 << 2];
      accd += (double)mv.x * bv.x + (double)mv.y * bv.y +
              (double)mv.z * bv.z + (double)mv.w * bv.w;
    }
    double xvv = 0.0;
    for (int j = 0; j < 64; ++j) {
      if (i == j) xvv = accd / (-(double)(j + 1));
      double xj = __shfl(xvv, j, 64);
      double pj = __shfl(pi, j, 64);
      if (i > j) accd += pi * pj * xj;  // accd -= Aval(i,j)*xj
    }
    b0[i] = (float)xvv;  // Vt[0] = B_bar  (Vt: stride 64, XOR-swizzled)
    // M_0 fp32 diag (I + E) for V-scan matvecs
    b1[(i << 6) + (i ^ (i & 28))] += 1.0f;
  }
  __syncthreads();

  // V doubling: v_{t+2^k} = M_k v_t (fp32 M from b1), then square.
  for (int k = 0; k < 6; ++k) {
    int cnt = 1 << k;
    for (int t = wv; t < cnt; t += 16) {
      float a0 = 0.f, a1 = 0.f;
#pragma unroll
      for (int k4 = 0; k4 < 16; ++k4) {
        int jM = (k4 << 2) ^ (lane & 28);
        f32x4 mv = *(const f32x4*)&b1[(lane << 6) + jM];
        f32x4 vvv = *(const f32x4*)&b0[(t << 6) + ((k4 << 2) ^ (t & 28))];
        a0 = fmaf(mv[0], vvv[0], fmaf(mv[1], vvv[1], a0));
        a1 = fmaf(mv[2], vvv[2], fmaf(mv[3], vvv[3], a1));
      }
      int td = t + cnt;
      b0[(td << 6) + (lane ^ (td & 28))] = a0 + a1;
    }
    // square M_k -> M_{k+1} (splits + fp32 b1); first barrier covers matvec
    mmMFMA(RH, RL, CH, CL, CH, CL, RH, RL, b1, nullptr, 0.f, 0.f, tid);
  }

  // W init: w_0 = C  (Wt: b1, plain stride 64; fp32 M_6 dead)
  if (tid < 64) b1[tid] = C_ssm[tid];
  __syncthreads();
  // W doubling (column-form splits, untransposed): w'[i] = sum_j w[j] M[j][i]
  for (int k = 0; k < 5; ++k) {
    int cnt = 1 << k;
    for (int t = wv; t < cnt; t += 16) {
      float ah = 0.f, al = 0.f;
#pragma unroll
      for (int kg = 0; kg < 8; ++kg) {
        short8 ch8 = *(const short8*)&CH[slotU(lane, kg)];
        short8 cl8 = *(const short8*)&CL[slotU(lane, kg)];
        f32x4 w0 = *(const f32x4*)&b1[(t << 6) + (kg << 3)];
        f32x4 w1 = *(const f32x4*)&b1[(t << 6) + (kg << 3) + 4];
#pragma unroll
        for (int j = 0; j < 4; ++j) {
          ah = fmaf(bf2f((unsigned short)ch8[j]), w0[j], ah);
          al = fmaf(bf2f((unsigned short)cl8[j]), w0[j], al);
        }
#pragma unroll
        for (int j = 0; j < 4; ++j) {
          ah = fmaf(bf2f((unsigned short)ch8[4 + j]), w1[j], ah);
          al = fmaf(bf2f((unsigned short)cl8[4 + j]), w1[j], al);
        }
      }
      b1[((t + cnt) << 6) + lane] = ah + al;
    }
    if (k < 3) {
      mmMFMA(RH, RL, CH, CL, CH, CL, RH, RL, nullptr, nullptr, 0.f, 0.f, tid);
    } else if (k == 3) {
      // M_10 only consumed col-form by level-4 matvec
      mmMFMA(RH, RL, CH, CL, CH, CL, nullptr, nullptr, nullptr, nullptr,
             0.f, 0.f, tid);
    } else {
      __syncthreads();  // after last matvec, before K overwrites b3
    }
  }

  // K[64t'+t] = w_t' . v_t  -> K in b3 (col-splits dead)
  float* K = b3;
  for (int x = tid; x < 2048; x += 1024) {
    int tp = x >> 6, t = x & 63;
    float d0 = 0.f, d1 = 0.f;
#pragma unroll
    for (int i4 = 0; i4 < 64; i4 += 4) {
      f32x4 wv4 = *(const f32x4*)&b1[(tp << 6) + i4];
      f32x4 vv4 = *(const f32x4*)&b0[(t << 6) + (i4 ^ (t & 28))];
      d0 = fmaf(wv4[0], vv4[0], fmaf(wv4[1], vv4[1], d0));
      d1 = fmaf(wv4[2], vv4[2], fmaf(wv4[3], vv4[3], d1));
    }
    K[x] = d0 + d1;
  }
  __syncthreads();

  // split (with D folded at x=2047) -> kh/kl (b2); suffix-energy partials
  unsigned short* kh = (unsigned short*)b2;
  unsigned short* kl = kh + 2192;
  float* ss = (float*)(kh + 4400);
  const float D = D_skip[0];
  for (int x = tid; x < 2192; x += 1024) {
    float v = 0.f;
    if (x < 2048) { v = K[x]; if (x == 2047) v += D; }
    unsigned h = rne_bf16(v);
    float hf2 = __uint_as_float(h << 16);
    unsigned l = rne_bf16(v - hf2);
    kh[x] = (unsigned short)h;
    kl[x] = (unsigned short)l;
  }
  if (tid < 256) {
    float ssum = 0.f;
#pragma unroll
    for (int q = 0; q < 8; ++q) {
      int x = (tid << 3) + q;
      float v = K[x];
      if (x == 2047) v += D;
      ssum += v * v;
    }
    ss[tid] = ssum;
  }
  __syncthreads();

  // ring tables: rg[e] = krev16[e..e+7]
  for (int e = tid; e < 2176; e += 1024) {
    unsigned ph[4], pl[4];
#pragma unroll
    for (int q2 = 0; q2 < 4; ++q2) {
      ph[q2] = (unsigned)kh[e + 2 * q2] | ((unsigned)kh[e + 2 * q2 + 1] << 16);
      pl[q2] = (unsigned)kl[e + 2 * q2] | ((unsigned)kl[e + 2 * q2 + 1] << 16);
    }
    rg_hi[e] = make_uint4(ph[0], ph[1], ph[2], ph[3]);
    rg_lo[e] = make_uint4(pl[0], pl[1], pl[2], pl[3]);
  }
  if (tid == 0) {
    float accq = 0.f;
    int xt = 0;
    for (int jc = 255; jc >= 0; --jc) {
      float na = accq + ss[jc];
      if (na > 4e-8f) { xt = (jc + 1) << 3; break; }
      accq = na;
    }
    wsi[0] = 2048 - xt;
  }
}

// ---------------------------------------------------------------------------
// conv kernel (unchanged from R7)
// ---------------------------------------------------------------------------
__device__ __forceinline__ void load_bfrag(short8* bf, const uint4* ubf,
                                           const float* u, int use_ubf, int b,
                                           int kt, int h0, int wn, int lane) {
  if (use_ubf) {
    const short8* base = (const short8*)(ubf + ((((b << 6) | kt) << 11) |
                                               (((h0 >> 4) + (wn << 2)) << 6) |
                                               lane));
#pragma unroll
    for (int j = 0; j < 4; ++j) bf[j] = base[j << 6];
  } else {
    int gg = lane >> 4, hm = lane & 15;
#pragma unroll
    for (int j = 0; j < 4; ++j) {
      const float* src = u + ((((b << 11) + (kt << 5) + (gg << 3)) << 9) + h0 +
                              (((wn << 2) + j) << 4) + hm);
      unsigned pk[4];
#pragma unroll
      for (int q = 0; q < 4; ++q) {
        unsigned lo = rne_bf16(src[q << 10]);
        unsigned hi = rne_bf16(src[(q << 10) + 512]);
        pk[q] = lo | (hi << 16);
      }
      uint4 vv = make_uint4(pk[0], pk[1], pk[2], pk[3]);
      bf[j] = __builtin_bit_cast(short8, vv);
    }
  }
}

__global__ __launch_bounds__(256) void conv_kernel(
    const float* __restrict__ u, const uint4* __restrict__ rg_hi,
    const uint4* __restrict__ rg_lo, const uint4* __restrict__ ubf,
    const int* __restrict__ wsi, float* __restrict__ y, int use_ubf) {
  __shared__ __align__(16) unsigned ringh[1024], ringl[1024];  // 256x16B each
  const int tid = threadIdx.x;
  // XCD-aware bijective swizzle (8 XCDs, 512 blocks): XCD x works on logical
  // blocks [64x, 64x+64) = exactly 2 batches -> ubf working set 4MB = L2.
  const int bid0 = blockIdx.x;
  const int bid = ((bid0 & 7) << 6) | (bid0 >> 3);
  const int b = bid >> 5;
  const int bn = bid & 3;
  const int pr = (bid >> 2) & 7;
  const int h0 = bn << 7;
  const int lane = tid & 63, w = tid >> 6;
  const int wm = w & 1, wn = w >> 1;
  const int g = lane >> 4, m = lane & 15;
  const int D_lo = wsi[0];

  for (int tile = 0; tile < 2; ++tile) {
    const int bm = tile ? pr : 15 - pr;
    const int l0 = bm << 7;
    const int e0 = 1920 - l0;
    const int ktiles = 4 * bm + 4;
    int kt_lim = ((l0 + 127 - D_lo) >> 5) + 1;
    if (kt_lim < 0) kt_lim = 0;
    if (kt_lim > ktiles) kt_lim = ktiles;

    __syncthreads();  // previous tile's ring reads complete
    for (int tsk = tid; tsk < 432; tsk += 256) {
      int isLo = tsk >= 216;
      int e = e0 + (isLo ? tsk - 216 : tsk);
      if (e <= 2175) {
        uint4 v = isLo ? rg_lo[e] : rg_hi[e];
        ((uint4*)(isLo ? ringl : ringh))[e & 255] = v;
      }
    }

    f32x4 acc[4][4];
#pragma unroll
    for (int i = 0; i < 4; ++i)
#pragma unroll
      for (int j = 0; j < 4; ++j) acc[i][j] = (f32x4){0.f, 0.f, 0.f, 0.f};

    short8 bcur[4];
    if (kt_lim > 0) load_bfrag(bcur, ubf, u, use_ubf, b, 0, h0, wn, lane);

    for (int kt = 0; kt < kt_lim; ++kt) {
      __syncthreads();  // ring writes visible
      uint4 tv;
      bool tdo = false;
      int tslot = 0;
      const bool tlo = (tid >= 32);
      if (tid < 64) {
        int te = e0 + 216 + (kt << 5) + (tid & 31);
        if (te <= 2175) {
          tv = tlo ? rg_lo[te] : rg_hi[te];
          tdo = true;
          tslot = te & 255;
        }
      }
      const int ebase = 2047 - l0 + (kt << 5) - (wm << 6) - m + (g << 3);
      short8 ah[4], al[4];
#pragma unroll
      for (int i = 0; i < 4; ++i) {
        int slot = (ebase - (i << 4)) & 255;
        ah[i] = ((const short8*)ringh)[slot];
        al[i] = ((const short8*)ringl)[slot];
      }
      short8 bnx[4];
      if (kt + 1 < kt_lim)
        load_bfrag(bnx, ubf, u, use_ubf, b, kt + 1, h0, wn, lane);
#pragma unroll
      for (int i = 0; i < 4; ++i)
#pragma unroll
        for (int j = 0; j < 4; ++j) {
          acc[i][j] = __builtin_amdgcn_mfma_f32_16x16x32_bf16(ah[i], bcur[j],
                                                              acc[i][j], 0, 0, 0);
          acc[i][j] = __builtin_amdgcn_mfma_f32_16x16x32_bf16(al[i], bcur[j],
                                                              acc[i][j], 0, 0, 0);
        }
      if (tdo) ((uint4*)(tlo ? ringl : ringh))[tslot] = tv;
      if (kt + 1 < kt_lim) {
#pragma unroll
        for (int j = 0; j < 4; ++j) bcur[j] = bnx[j];
      }
    }

    // epilogue: y = acc  (D folded into K); C/D: col=lane&15, row=g*4+reg
#pragma unroll
    for (int i = 0; i < 4; ++i)
#pragma unroll
      for (int j = 0; j < 4; ++j) {
        int l = l0 + (wm << 6) + (i << 4) + (g << 2);
        int h = h0 + (((wn << 2) + j) << 4) + m;
        int off = (((b << 11) + l) << 9) + h;
#pragma unroll
        for (int r = 0; r < 4; ++r) y[off + (r << 9)] = acc[i][j][r];
      }
  }
}

extern "C" void kernel_launch(void* const* d_in, const int* in_sizes, int n_in,
                              void* d_out, int out_size, void* d_ws,
                              size_t ws_size, hipStream_t stream) {
  (void)in_sizes; (void)n_in; (void)out_size;
  const float* u = (const float*)d_in[0];
  const float* B_ssm = (const float*)d_in[1];
  const float* C_ssm = (const float*)d_in[2];
  const float* D_skip = (const float*)d_in[3];
  const float* log_dt = (const float*)d_in[4];
  float* y = (float*)d_out;

  const size_t UBF_BYTES = (size_t)16 * 64 * 2048 * 16;  // 32 MB
  const size_t RG_BYTES = (size_t)2176 * 16 * 2 + 256;
  int use_ubf = (ws_size >= UBF_BYTES + RG_BYTES) ? 1 : 0;
  char* wsb = (char*)d_ws;
  uint4* ubf = (uint4*)wsb;
  uint4* rg_hi = use_ubf ? (uint4*)(wsb + UBF_BYTES) : (uint4*)wsb;
  uint4* rg_lo = rg_hi + 2176;
  int* wsi = (int*)(rg_lo + 2176);

  prep_quant<<<use_ubf ? 2049 : 1, 1024, 0, stream>>>(
      u, B_ssm, C_ssm, D_skip, log_dt, rg_hi, rg_lo, wsi, ubf);
  conv_kernel<<<512, 256, 0, stream>>>(u, rg_hi, rg_lo, ubf, wsi, y, use_ubf);
}